// Round 13
// baseline (149.805 us; speedup 1.0000x reference)
//
#include <hip/hip_runtime.h>

typedef __attribute__((ext_vector_type(8))) short bf16x8;
typedef __attribute__((ext_vector_type(4))) float f32x4;
typedef __attribute__((ext_vector_type(4))) unsigned short us4;

__device__ __forceinline__ unsigned short f2bf(float f) {
    unsigned int u = __builtin_bit_cast(unsigned int, f);
    u = (u + 0x7FFFu + ((u >> 16) & 1u)) >> 16;
    return (unsigned short)u;
}
__device__ __forceinline__ float bf2f(unsigned short h) {
    return __builtin_bit_cast(float, (unsigned int)h << 16);
}

// ---------------- fold BN into weights, emit bf16; per-head packed row order ----------------
__global__ __launch_bounds__(256) void fold_weights_k(
    const float* __restrict__ Wq, const float* __restrict__ sq, const float* __restrict__ bq,
    const float* __restrict__ Wk, const float* __restrict__ sk, const float* __restrict__ bk,
    const float* __restrict__ Wv, const float* __restrict__ sv, const float* __restrict__ bv,
    const float* __restrict__ Wp, const float* __restrict__ sp,
    unsigned short* __restrict__ WqkvP, unsigned short* __restrict__ Wpf, float* __restrict__ bqkvP)
{
    int i = blockIdx.x * 256 + threadIdx.x;
    if (i < 393216) {                       // WqkvP [1024][384]
        int r = i / 384, c = i - r * 384;
        int head = r >> 7, t = r & 127;
        float w, s;
        if (t < 32)      { int ch = head * 32 + t;        w = Wq[ch * 384 + c]; s = sq[ch]; }
        else if (t < 64) { int ch = head * 32 + (t - 32); w = Wk[ch * 384 + c]; s = sk[ch]; }
        else             { int ch = head * 64 + (t - 64); w = Wv[ch * 384 + c]; s = sv[ch]; }
        WqkvP[i] = f2bf(w * s);
    } else if (i < 589824) {                // Wpf [384][512]
        int j = i - 393216;
        Wpf[j] = f2bf(Wp[j] * sp[j >> 9]);
    } else if (i < 590848) {
        int r = i - 589824;
        int head = r >> 7, t = r & 127;
        bqkvP[r] = (t < 32) ? bq[head * 32 + t]
                 : (t < 64) ? bk[head * 32 + (t - 32)]
                            : bv[head * 64 + (t - 64)];
    }
}

// ---------------- fused QKV GEMM (x read directly, transpose in-LDS) + context partials ----------------
__global__ __launch_bounds__(256, 3) void gemm_qkv_k(
    const unsigned short* __restrict__ A,     // WqkvP [1024][384] head-packed
    const float* __restrict__ x,              // [b][384][4096] f32
    const float* __restrict__ bias,           // bqkvP
    unsigned short* __restrict__ q_out,       // qT [b][4096][256]
    float* __restrict__ part,                 // [32][64][2048]
    float* __restrict__ psums)                // [32][64][32]
{
    __shared__ unsigned short As[3 * 4096];
    __shared__ unsigned short Bs[3 * 4096];
    const int tid = threadIdx.x;
    const int lane = tid & 63;
    const int w = tid >> 6, wr = w >> 1, wc = w & 1;
    const int li = lane & 15, g = lane >> 4;
    const int b = blockIdx.z, head = blockIdx.y, chunk = blockIdx.x;
    const int n0 = chunk * 128, m0 = head * 128;
    const float* xb = x + (long)b * 384 * 4096 + n0 + 2 * lane;

    const int i0 = tid, i1 = tid + 256;
    const int p0 = i0 >> 3, v0 = (i0 & 7) ^ (p0 & 7);
    const int p1 = i1 >> 3, v1 = (i1 & 7) ^ (p1 & 7);
    const long aro0 = (long)m0 * 384 + (long)(p0 * 2 + (v0 >> 2)) * 384 + (v0 & 3) * 8;
    const long aro1 = (long)m0 * 384 + (long)(p1 * 2 + (v1 >> 2)) * 384 + (v1 & 3) * 8;

#define ISSUE_A(kt) { const int _bf = (kt) % 3; const int _k0 = (kt) * 32; \
    __builtin_amdgcn_global_load_lds( \
        (const __attribute__((address_space(1))) void*)(A + aro0 + _k0), \
        (__attribute__((address_space(3))) void*)(As + _bf * 4096 + (size_t)i0 * 8), 16, 0, 0); \
    __builtin_amdgcn_global_load_lds( \
        (const __attribute__((address_space(1))) void*)(A + aro1 + _k0), \
        (__attribute__((address_space(3))) void*)(As + _bf * 4096 + (size_t)i1 * 8), 16, 0, 0); }

#define ISSUE_B(kt, breg) { const int _k0 = (kt) * 32 + w * 8; \
    _Pragma("unroll") \
    for (int j = 0; j < 8; ++j) \
        breg[j] = *reinterpret_cast<const float2*>(xb + (long)(_k0 + j) * 4096); }

#define WRITE_B(breg, _bf) { \
    bf16x8 pk0, pk1; \
    _Pragma("unroll") \
    for (int j = 0; j < 8; ++j) { \
        pk0[j] = (short)f2bf(breg[j].x); pk1[j] = (short)f2bf(breg[j].y); } \
    int s0 = w ^ (lane & 7), s1 = (4 + w) ^ (lane & 7); \
    *reinterpret_cast<bf16x8*>(Bs + (_bf) * 4096 + lane * 64 + s0 * 8) = pk0; \
    *reinterpret_cast<bf16x8*>(Bs + (_bf) * 4096 + lane * 64 + s1 * 8) = pk1; }

    float2 bregA[8], bregB[8];
    ISSUE_A(0); ISSUE_B(0, bregA);
    ISSUE_A(1); ISSUE_B(1, bregB);
    WRITE_B(bregA, 0);
    asm volatile("s_waitcnt vmcnt(10) lgkmcnt(0)\n\ts_barrier" ::: "memory");
    __builtin_amdgcn_sched_barrier(0);

    f32x4 acc[4][4];
    #pragma unroll
    for (int i = 0; i < 4; ++i)
        #pragma unroll
        for (int j = 0; j < 4; ++j) acc[i][j] = (f32x4){0.f, 0.f, 0.f, 0.f};

    #pragma unroll
    for (int kt = 0; kt < 12; ++kt) {
        const unsigned short* Ab = As + (kt % 3) * 4096;
        const unsigned short* Bl = Bs + (kt % 3) * 4096;

        bf16x8 av[4], bv[4];
        #pragma unroll
        for (int mf = 0; mf < 4; ++mf) {
            int r = wr * 64 + mf * 16 + li;
            int p = r >> 1;
            int slot = (((r & 1) * 4 + g) ^ (p & 7));
            av[mf] = *reinterpret_cast<const bf16x8*>(Ab + p * 64 + slot * 8);
        }
        #pragma unroll
        for (int nf = 0; nf < 4; ++nf) {
            int r = wc * 64 + nf * 16 + li;
            int p = r >> 1;
            int slot = (((r & 1) * 4 + g) ^ (p & 7));
            bv[nf] = *reinterpret_cast<const bf16x8*>(Bl + p * 64 + slot * 8);
        }
        if (kt < 10) {
            ISSUE_A(kt + 2);
            if (kt & 1) { ISSUE_B(kt + 2, bregB) }
            else        { ISSUE_B(kt + 2, bregA) }
        }
        __builtin_amdgcn_s_setprio(1);
        #pragma unroll
        for (int mf = 0; mf < 4; ++mf)
            #pragma unroll
            for (int nf = 0; nf < 4; ++nf)
                acc[mf][nf] = __builtin_amdgcn_mfma_f32_16x16x32_bf16(av[mf], bv[nf], acc[mf][nf], 0, 0, 0);
        __builtin_amdgcn_s_setprio(0);
        if (kt < 11) {
            if (kt & 1) { WRITE_B(bregA, (kt + 1) % 3) }
            else        { WRITE_B(bregB, (kt + 1) % 3) }
            asm volatile("s_waitcnt lgkmcnt(0)\n\ts_barrier" ::: "memory");
            __builtin_amdgcn_sched_barrier(0);
        }
    }
#undef ISSUE_A
#undef ISSUE_B
#undef WRITE_B

    __syncthreads();

    unsigned short* Ksh = As;
    unsigned short* Vsh = As + 4096;
    float* psl = reinterpret_cast<float*>(Bs);   // [2][32]

    if (wr == 0) {
        #pragma unroll
        for (int mf = 0; mf < 2; ++mf) {
            int ml = mf * 16 + g * 4;
            #pragma unroll
            for (int nf = 0; nf < 4; ++nf) {
                int n = n0 + wc * 64 + nf * 16 + li;
                f32x4 v = acc[mf][nf];
                us4 o = { f2bf(v.x + bias[m0 + ml]),     f2bf(v.y + bias[m0 + ml + 1]),
                          f2bf(v.z + bias[m0 + ml + 2]), f2bf(v.w + bias[m0 + ml + 3]) };
                *reinterpret_cast<us4*>(q_out + (((long)b * 4096 + n) << 8) + head * 32 + ml) = o;
            }
        }
        float rs[2][4] = {{0.f,0.f,0.f,0.f},{0.f,0.f,0.f,0.f}};
        #pragma unroll
        for (int mm = 0; mm < 2; ++mm) {
            #pragma unroll
            for (int nf = 0; nf < 4; ++nf) {
                int nl = wc * 64 + nf * 16 + li;
                f32x4 v = acc[mm + 2][nf];
                #pragma unroll
                for (int r = 0; r < 4; ++r) {
                    int kd = mm * 16 + g * 4 + r;
                    float e = __expf(v[r] + bias[m0 + 32 + kd]);
                    rs[mm][r] += e;
                    Ksh[kd * 128 + ((((nl >> 3) ^ (kd & 7)) << 3) | (nl & 7))] = f2bf(e);
                }
            }
        }
        #pragma unroll
        for (int mm = 0; mm < 2; ++mm)
            #pragma unroll
            for (int r = 0; r < 4; ++r) {
                float s = rs[mm][r];
                s += __shfl_xor(s, 1); s += __shfl_xor(s, 2);
                s += __shfl_xor(s, 4); s += __shfl_xor(s, 8);
                if (li == 0) psl[wc * 32 + mm * 16 + g * 4 + r] = s;
            }
    } else {
        #pragma unroll
        for (int mf = 0; mf < 4; ++mf) {
            #pragma unroll
            for (int nf = 0; nf < 4; ++nf) {
                int nl = wc * 64 + nf * 16 + li;
                f32x4 v = acc[mf][nf];
                #pragma unroll
                for (int r = 0; r < 4; ++r) {
                    int d = mf * 16 + g * 4 + r;
                    Vsh[d * 128 + ((((nl >> 3) ^ (d & 7)) << 3) | (nl & 7))] =
                        f2bf(v[r] + bias[m0 + 64 + d]);
                }
            }
        }
    }
    __syncthreads();

    f32x4 c2[2] = {(f32x4){0.f,0.f,0.f,0.f}, (f32x4){0.f,0.f,0.f,0.f}};
    #pragma unroll
    for (int ks = 0; ks < 4; ++ks) {
        int rd = w * 16 + li;
        bf16x8 a0 = *reinterpret_cast<const bf16x8*>(Ksh + li * 128        + ((((ks * 4 + g) ^ (li & 7)) << 3)));
        bf16x8 a1 = *reinterpret_cast<const bf16x8*>(Ksh + (16 + li) * 128 + ((((ks * 4 + g) ^ ((16 + li) & 7)) << 3)));
        bf16x8 bb = *reinterpret_cast<const bf16x8*>(Vsh + rd * 128        + ((((ks * 4 + g) ^ (rd & 7)) << 3)));
        c2[0] = __builtin_amdgcn_mfma_f32_16x16x32_bf16(a0, bb, c2[0], 0, 0, 0);
        c2[1] = __builtin_amdgcn_mfma_f32_16x16x32_bf16(a1, bb, c2[1], 0, 0, 0);
    }
    const int bh = b * 8 + head;
    const long pbase = ((long)chunk * 64 + bh) * 2048;
    #pragma unroll
    for (int mm = 0; mm < 2; ++mm)
        #pragma unroll
        for (int r = 0; r < 4; ++r)
            part[pbase + (mm * 16 + g * 4 + r) * 64 + w * 16 + li] = c2[mm][r];
    if (tid < 32)
        psums[((long)chunk * 64 + bh) * 32 + tid] = psl[tid] + psl[32 + tid];
}

// ---------------- reduce 32 chunks, normalize -> ctxT[bh][d][kd] bf16 ----------------
__global__ __launch_bounds__(256) void ctx_reduce_k(const float* __restrict__ part,
                                                    const float* __restrict__ psums,
                                                    unsigned short* __restrict__ ctxT)
{
    int t = blockIdx.x * 256 + threadIdx.x;   // < 131072
    int bh = t >> 11, i = t & 2047;
    int kd = i & 31, d = i >> 5;
    float s = 0.f, den = 0.f;
    #pragma unroll
    for (int c = 0; c < 32; ++c) {
        s   += part[((long)c * 64 + bh) * 2048 + kd * 64 + d];
        den += psums[((long)c * 64 + bh) * 32 + kd];
    }
    ctxT[t] = f2bf(s / den);
}

// ---------------- proj v6: tall-M, single-buffered As (issue-early), 2 blocks/CU ----------------
// grid (32 n-blocks, 8 b), 512 threads = 8 waves. LDS = As 48 KB + Bsh 16 KB = 64 KB.
// Per step: barrier -> ISSUE As stage -> attend (covers load latency) -> vmcnt(0)+barrier -> GEMM.
__global__ __launch_bounds__(512, 4) void proj_fused_k(
    const unsigned short* __restrict__ Wpf,   // [384][512] bf16, k = h*64+d
    const unsigned short* __restrict__ qT,    // [b][4096][256] bf16 (raw q, pre-softmax)
    const unsigned short* __restrict__ ctxT,  // [b*8+h][64 d][32 kd] bf16
    const float* __restrict__ bp,
    float* __restrict__ out)                  // [b][384][4096] f32
{
    __shared__ unsigned short Bsh[128 * 64];
    __shared__ unsigned short As[384 * 64];
    const int tid = threadIdx.x, lane = tid & 63, w = tid >> 6;
    const int li = lane & 15, g = lane >> 4;
    const int b = blockIdx.y, n0 = blockIdx.x * 128;

#define PROJ_STAGE(s) { \
    _Pragma("unroll") \
    for (int j = 0; j < 6; ++j) { \
        int idx = j * 512 + tid; \
        int r = idx >> 3; \
        int ls = ((idx & 7) ^ (r & 7)) * 8; \
        __builtin_amdgcn_global_load_lds( \
            (const __attribute__((address_space(1))) void*)(Wpf + (long)r * 512 + (s) * 64 + ls), \
            (__attribute__((address_space(3))) void*)(As + (size_t)idx * 8), 16, 0, 0); \
    } }

    f32x4 acc[3][8];
    #pragma unroll
    for (int i = 0; i < 3; ++i)
        #pragma unroll
        for (int j = 0; j < 8; ++j) acc[i][j] = (f32x4){0.f, 0.f, 0.f, 0.f};

    for (int s = 0; s < 8; ++s) {
        if (s > 0) __syncthreads();          // prior GEMM's As/Bsh reads complete
        PROJ_STAGE(s);                       // issue As loads; latency covered by attend below

        // ---- attend: A = ctxT_s, B = softmax(q) in-register (no As dependency)
        const unsigned short* cb = ctxT + ((long)b * 8 + s) * 2048;
        bf16x8 ca[4], pb;
        #pragma unroll
        for (int df = 0; df < 4; ++df)
            ca[df] = *reinterpret_cast<const bf16x8*>(cb + (df * 16 + li) * 32 + g * 8);
        {
            int n = n0 + w * 16 + li;
            bf16x8 r = *reinterpret_cast<const bf16x8*>(
                qT + (((long)b * 4096 + n) << 8) + s * 32 + g * 8);
            float f[8];
            float mx = -1e30f;
            #pragma unroll
            for (int j = 0; j < 8; ++j) { f[j] = bf2f((unsigned short)r[j]); mx = fmaxf(mx, f[j]); }
            mx = fmaxf(mx, __shfl_xor(mx, 16));
            mx = fmaxf(mx, __shfl_xor(mx, 32));
            float sm = 0.f;
            #pragma unroll
            for (int j = 0; j < 8; ++j) { f[j] = __expf(f[j] - mx); sm += f[j]; }
            sm += __shfl_xor(sm, 16);
            sm += __shfl_xor(sm, 32);
            float inv = 1.f / sm;
            #pragma unroll
            for (int j = 0; j < 8; ++j) pb[j] = (short)f2bf(f[j] * inv);
        }
        #pragma unroll
        for (int df = 0; df < 4; ++df) {
            f32x4 d = (f32x4){0.f, 0.f, 0.f, 0.f};
            d = __builtin_amdgcn_mfma_f32_16x16x32_bf16(ca[df], pb, d, 0, 0, 0);
            us4 o = { f2bf(fmaxf(d.x, 0.f)), f2bf(fmaxf(d.y, 0.f)),
                      f2bf(fmaxf(d.z, 0.f)), f2bf(fmaxf(d.w, 0.f)) };
            int n = w * 16 + li;
            int slot = (df * 2 + (g >> 1)) ^ (n & 7);
            *reinterpret_cast<us4*>(Bsh + n * 64 + slot * 8 + (g & 1) * 4) = o;
        }

        // As data landed + Bsh visible
        asm volatile("s_waitcnt vmcnt(0) lgkmcnt(0)\n\ts_barrier" ::: "memory");
        __builtin_amdgcn_sched_barrier(0);

        // ---- GEMM: wave w owns m-rows w*48..+48 x n 0..128
        #pragma unroll
        for (int kk = 0; kk < 2; ++kk) {
            bf16x8 av[3], bv[8];
            #pragma unroll
            for (int mf = 0; mf < 3; ++mf) {
                int row = w * 48 + mf * 16 + li;
                int ps = ((kk * 4 + g) ^ (row & 7)) * 8;
                av[mf] = *reinterpret_cast<const bf16x8*>(As + row * 64 + ps);
            }
            #pragma unroll
            for (int nf = 0; nf < 8; ++nf) {
                int nn = nf * 16 + li;
                int ps = ((kk * 4 + g) ^ (nn & 7)) * 8;
                bv[nf] = *reinterpret_cast<const bf16x8*>(Bsh + nn * 64 + ps);
            }
            #pragma unroll
            for (int mf = 0; mf < 3; ++mf)
                #pragma unroll
                for (int nf = 0; nf < 8; ++nf)
                    acc[mf][nf] = __builtin_amdgcn_mfma_f32_16x16x32_bf16(av[mf], bv[nf], acc[mf][nf], 0, 0, 0);
        }
    }
#undef PROJ_STAGE

    #pragma unroll
    for (int mf = 0; mf < 3; ++mf) {
        int m = w * 48 + mf * 16 + g * 4;
        #pragma unroll
        for (int nf = 0; nf < 8; ++nf) {
            int n = n0 + nf * 16 + li;
            f32x4 v = acc[mf][nf];
            #pragma unroll
            for (int r = 0; r < 4; ++r)
                out[((long)b * 384 + m + r) * 4096 + n] = v[r] + bp[m + r];
        }
    }
}

// ---------------- launch ----------------
extern "C" void kernel_launch(void* const* d_in, const int* in_sizes, int n_in,
                              void* d_out, int out_size, void* d_ws, size_t ws_size,
                              hipStream_t stream) {
    (void)in_sizes; (void)n_in; (void)out_size; (void)ws_size;
    const float* x  = (const float*)d_in[0];
    const float* Wq = (const float*)d_in[1];
    const float* sq = (const float*)d_in[2];
    const float* bq = (const float*)d_in[3];
    const float* Wk = (const float*)d_in[4];
    const float* sk = (const float*)d_in[5];
    const float* bk = (const float*)d_in[6];
    const float* Wv = (const float*)d_in[7];
    const float* sv = (const float*)d_in[8];
    const float* bv = (const float*)d_in[9];
    const float* Wp = (const float*)d_in[10];
    const float* sp = (const float*)d_in[11];
    const float* bp = (const float*)d_in[12];
    float* out = (float*)d_out;

    char* wsb = (char*)d_ws;
    unsigned short* Wqkv  = (unsigned short*)(wsb);              // 786432 B
    unsigned short* Wpf   = (unsigned short*)(wsb + 786432);     // 393216 B
    float*          bqkv  = (float*)(wsb + 1179648);             // 4096 B
    unsigned short* ctxT  = (unsigned short*)(wsb + 1183744);    // 262144 B
    float*          part  = (float*)(wsb + 1445888);             // 16777216 B
    float*          psums = (float*)(wsb + 18223104);            // 262144 B
    unsigned short* qT    = (unsigned short*)(wsb + 18485248);   // 16777216 B -> 35.3 MB total

    fold_weights_k<<<2308, 256, 0, stream>>>(Wq, sq, bq, Wk, sk, bk, Wv, sv, bv, Wp, sp,
                                             Wqkv, Wpf, bqkv);
    gemm_qkv_k<<<dim3(32, 8, 8), 256, 0, stream>>>(Wqkv, x, bqkv, qT, part, psums);
    ctx_reduce_k<<<512, 256, 0, stream>>>(part, psums, ctxT);
    proj_fused_k<<<dim3(32, 8), 512, 0, stream>>>(Wpf, qT, ctxT, bp, out);
}

// Round 14
// 98.385 us; speedup vs baseline: 1.5226x; 1.5226x over previous
//
#include <hip/hip_runtime.h>

typedef __attribute__((ext_vector_type(8))) short bf16x8;
typedef __attribute__((ext_vector_type(4))) float f32x4;
typedef __attribute__((ext_vector_type(4))) unsigned short us4;

__device__ __forceinline__ unsigned short f2bf(float f) {
    unsigned int u = __builtin_bit_cast(unsigned int, f);
    u = (u + 0x7FFFu + ((u >> 16) & 1u)) >> 16;
    return (unsigned short)u;
}
__device__ __forceinline__ float bf2f(unsigned short h) {
    return __builtin_bit_cast(float, (unsigned int)h << 16);
}

// ---------------- fold BN into weights, emit bf16; per-head packed row order ----------------
__global__ __launch_bounds__(256) void fold_weights_k(
    const float* __restrict__ Wq, const float* __restrict__ sq, const float* __restrict__ bq,
    const float* __restrict__ Wk, const float* __restrict__ sk, const float* __restrict__ bk,
    const float* __restrict__ Wv, const float* __restrict__ sv, const float* __restrict__ bv,
    const float* __restrict__ Wp, const float* __restrict__ sp,
    unsigned short* __restrict__ WqkvP, unsigned short* __restrict__ Wpf, float* __restrict__ bqkvP)
{
    int i = blockIdx.x * 256 + threadIdx.x;
    if (i < 393216) {                       // WqkvP [1024][384]
        int r = i / 384, c = i - r * 384;
        int head = r >> 7, t = r & 127;
        float w, s;
        if (t < 32)      { int ch = head * 32 + t;        w = Wq[ch * 384 + c]; s = sq[ch]; }
        else if (t < 64) { int ch = head * 32 + (t - 32); w = Wk[ch * 384 + c]; s = sk[ch]; }
        else             { int ch = head * 64 + (t - 64); w = Wv[ch * 384 + c]; s = sv[ch]; }
        WqkvP[i] = f2bf(w * s);
    } else if (i < 589824) {                // Wpf [384][512]
        int j = i - 393216;
        Wpf[j] = f2bf(Wp[j] * sp[j >> 9]);
    } else if (i < 590848) {
        int r = i - 589824;
        int head = r >> 7, t = r & 127;
        bqkvP[r] = (t < 32) ? bq[head * 32 + t]
                 : (t < 64) ? bk[head * 32 + (t - 32)]
                            : bv[head * 64 + (t - 64)];
    }
}

// ---------------- fused QKV GEMM (x read directly, transpose in-LDS) + context partials ----------------
__global__ __launch_bounds__(256, 3) void gemm_qkv_k(
    const unsigned short* __restrict__ A,     // WqkvP [1024][384] head-packed
    const float* __restrict__ x,              // [b][384][4096] f32
    const float* __restrict__ bias,           // bqkvP
    unsigned short* __restrict__ q_out,       // qT [b][4096][256]
    float* __restrict__ part,                 // [32][64][2048]
    float* __restrict__ psums)                // [32][64][32]
{
    __shared__ unsigned short As[3 * 4096];
    __shared__ unsigned short Bs[3 * 4096];
    const int tid = threadIdx.x;
    const int lane = tid & 63;
    const int w = tid >> 6, wr = w >> 1, wc = w & 1;
    const int li = lane & 15, g = lane >> 4;
    const int b = blockIdx.z, head = blockIdx.y, chunk = blockIdx.x;
    const int n0 = chunk * 128, m0 = head * 128;
    const float* xb = x + (long)b * 384 * 4096 + n0 + 2 * lane;

    const int i0 = tid, i1 = tid + 256;
    const int p0 = i0 >> 3, v0 = (i0 & 7) ^ (p0 & 7);
    const int p1 = i1 >> 3, v1 = (i1 & 7) ^ (p1 & 7);
    const long aro0 = (long)m0 * 384 + (long)(p0 * 2 + (v0 >> 2)) * 384 + (v0 & 3) * 8;
    const long aro1 = (long)m0 * 384 + (long)(p1 * 2 + (v1 >> 2)) * 384 + (v1 & 3) * 8;

#define ISSUE_A(kt) { const int _bf = (kt) % 3; const int _k0 = (kt) * 32; \
    __builtin_amdgcn_global_load_lds( \
        (const __attribute__((address_space(1))) void*)(A + aro0 + _k0), \
        (__attribute__((address_space(3))) void*)(As + _bf * 4096 + (size_t)i0 * 8), 16, 0, 0); \
    __builtin_amdgcn_global_load_lds( \
        (const __attribute__((address_space(1))) void*)(A + aro1 + _k0), \
        (__attribute__((address_space(3))) void*)(As + _bf * 4096 + (size_t)i1 * 8), 16, 0, 0); }

#define ISSUE_B(kt, breg) { const int _k0 = (kt) * 32 + w * 8; \
    _Pragma("unroll") \
    for (int j = 0; j < 8; ++j) \
        breg[j] = *reinterpret_cast<const float2*>(xb + (long)(_k0 + j) * 4096); }

#define WRITE_B(breg, _bf) { \
    bf16x8 pk0, pk1; \
    _Pragma("unroll") \
    for (int j = 0; j < 8; ++j) { \
        pk0[j] = (short)f2bf(breg[j].x); pk1[j] = (short)f2bf(breg[j].y); } \
    int s0 = w ^ (lane & 7), s1 = (4 + w) ^ (lane & 7); \
    *reinterpret_cast<bf16x8*>(Bs + (_bf) * 4096 + lane * 64 + s0 * 8) = pk0; \
    *reinterpret_cast<bf16x8*>(Bs + (_bf) * 4096 + lane * 64 + s1 * 8) = pk1; }

    float2 bregA[8], bregB[8];
    ISSUE_A(0); ISSUE_B(0, bregA);
    ISSUE_A(1); ISSUE_B(1, bregB);
    WRITE_B(bregA, 0);
    asm volatile("s_waitcnt vmcnt(10) lgkmcnt(0)\n\ts_barrier" ::: "memory");
    __builtin_amdgcn_sched_barrier(0);

    f32x4 acc[4][4];
    #pragma unroll
    for (int i = 0; i < 4; ++i)
        #pragma unroll
        for (int j = 0; j < 4; ++j) acc[i][j] = (f32x4){0.f, 0.f, 0.f, 0.f};

    #pragma unroll
    for (int kt = 0; kt < 12; ++kt) {
        const unsigned short* Ab = As + (kt % 3) * 4096;
        const unsigned short* Bl = Bs + (kt % 3) * 4096;

        bf16x8 av[4], bv[4];
        #pragma unroll
        for (int mf = 0; mf < 4; ++mf) {
            int r = wr * 64 + mf * 16 + li;
            int p = r >> 1;
            int slot = (((r & 1) * 4 + g) ^ (p & 7));
            av[mf] = *reinterpret_cast<const bf16x8*>(Ab + p * 64 + slot * 8);
        }
        #pragma unroll
        for (int nf = 0; nf < 4; ++nf) {
            int r = wc * 64 + nf * 16 + li;
            int p = r >> 1;
            int slot = (((r & 1) * 4 + g) ^ (p & 7));
            bv[nf] = *reinterpret_cast<const bf16x8*>(Bl + p * 64 + slot * 8);
        }
        if (kt < 10) {
            ISSUE_A(kt + 2);
            if (kt & 1) { ISSUE_B(kt + 2, bregB) }
            else        { ISSUE_B(kt + 2, bregA) }
        }
        __builtin_amdgcn_s_setprio(1);
        #pragma unroll
        for (int mf = 0; mf < 4; ++mf)
            #pragma unroll
            for (int nf = 0; nf < 4; ++nf)
                acc[mf][nf] = __builtin_amdgcn_mfma_f32_16x16x32_bf16(av[mf], bv[nf], acc[mf][nf], 0, 0, 0);
        __builtin_amdgcn_s_setprio(0);
        if (kt < 11) {
            if (kt & 1) { WRITE_B(bregA, (kt + 1) % 3) }
            else        { WRITE_B(bregB, (kt + 1) % 3) }
            asm volatile("s_waitcnt lgkmcnt(0)\n\ts_barrier" ::: "memory");
            __builtin_amdgcn_sched_barrier(0);
        }
    }
#undef ISSUE_A
#undef ISSUE_B
#undef WRITE_B

    __syncthreads();

    unsigned short* Ksh = As;
    unsigned short* Vsh = As + 4096;
    float* psl = reinterpret_cast<float*>(Bs);   // [2][32]

    if (wr == 0) {
        #pragma unroll
        for (int mf = 0; mf < 2; ++mf) {
            int ml = mf * 16 + g * 4;
            #pragma unroll
            for (int nf = 0; nf < 4; ++nf) {
                int n = n0 + wc * 64 + nf * 16 + li;
                f32x4 v = acc[mf][nf];
                us4 o = { f2bf(v.x + bias[m0 + ml]),     f2bf(v.y + bias[m0 + ml + 1]),
                          f2bf(v.z + bias[m0 + ml + 2]), f2bf(v.w + bias[m0 + ml + 3]) };
                *reinterpret_cast<us4*>(q_out + (((long)b * 4096 + n) << 8) + head * 32 + ml) = o;
            }
        }
        float rs[2][4] = {{0.f,0.f,0.f,0.f},{0.f,0.f,0.f,0.f}};
        #pragma unroll
        for (int mm = 0; mm < 2; ++mm) {
            #pragma unroll
            for (int nf = 0; nf < 4; ++nf) {
                int nl = wc * 64 + nf * 16 + li;
                f32x4 v = acc[mm + 2][nf];
                #pragma unroll
                for (int r = 0; r < 4; ++r) {
                    int kd = mm * 16 + g * 4 + r;
                    float e = __expf(v[r] + bias[m0 + 32 + kd]);
                    rs[mm][r] += e;
                    Ksh[kd * 128 + ((((nl >> 3) ^ (kd & 7)) << 3) | (nl & 7))] = f2bf(e);
                }
            }
        }
        #pragma unroll
        for (int mm = 0; mm < 2; ++mm)
            #pragma unroll
            for (int r = 0; r < 4; ++r) {
                float s = rs[mm][r];
                s += __shfl_xor(s, 1); s += __shfl_xor(s, 2);
                s += __shfl_xor(s, 4); s += __shfl_xor(s, 8);
                if (li == 0) psl[wc * 32 + mm * 16 + g * 4 + r] = s;
            }
    } else {
        #pragma unroll
        for (int mf = 0; mf < 4; ++mf) {
            #pragma unroll
            for (int nf = 0; nf < 4; ++nf) {
                int nl = wc * 64 + nf * 16 + li;
                f32x4 v = acc[mf][nf];
                #pragma unroll
                for (int r = 0; r < 4; ++r) {
                    int d = mf * 16 + g * 4 + r;
                    Vsh[d * 128 + ((((nl >> 3) ^ (d & 7)) << 3) | (nl & 7))] =
                        f2bf(v[r] + bias[m0 + 64 + d]);
                }
            }
        }
    }
    __syncthreads();

    f32x4 c2[2] = {(f32x4){0.f,0.f,0.f,0.f}, (f32x4){0.f,0.f,0.f,0.f}};
    #pragma unroll
    for (int ks = 0; ks < 4; ++ks) {
        int rd = w * 16 + li;
        bf16x8 a0 = *reinterpret_cast<const bf16x8*>(Ksh + li * 128        + ((((ks * 4 + g) ^ (li & 7)) << 3)));
        bf16x8 a1 = *reinterpret_cast<const bf16x8*>(Ksh + (16 + li) * 128 + ((((ks * 4 + g) ^ ((16 + li) & 7)) << 3)));
        bf16x8 bb = *reinterpret_cast<const bf16x8*>(Vsh + rd * 128        + ((((ks * 4 + g) ^ (rd & 7)) << 3)));
        c2[0] = __builtin_amdgcn_mfma_f32_16x16x32_bf16(a0, bb, c2[0], 0, 0, 0);
        c2[1] = __builtin_amdgcn_mfma_f32_16x16x32_bf16(a1, bb, c2[1], 0, 0, 0);
    }
    const int bh = b * 8 + head;
    const long pbase = ((long)chunk * 64 + bh) * 2048;
    #pragma unroll
    for (int mm = 0; mm < 2; ++mm)
        #pragma unroll
        for (int r = 0; r < 4; ++r)
            part[pbase + (mm * 16 + g * 4 + r) * 64 + w * 16 + li] = c2[mm][r];
    if (tid < 32)
        psums[((long)chunk * 64 + bh) * 32 + tid] = psl[tid] + psl[32 + tid];
}

// ---------------- reduce 32 chunks, normalize -> ctxT[bh][d][kd] bf16 ----------------
__global__ __launch_bounds__(256) void ctx_reduce_k(const float* __restrict__ part,
                                                    const float* __restrict__ psums,
                                                    unsigned short* __restrict__ ctxT)
{
    int t = blockIdx.x * 256 + threadIdx.x;   // < 131072
    int bh = t >> 11, i = t & 2047;
    int kd = i & 31, d = i >> 5;
    float s = 0.f, den = 0.f;
    #pragma unroll
    for (int c = 0; c < 32; ++c) {
        s   += part[((long)c * 64 + bh) * 2048 + kd * 64 + d];
        den += psums[((long)c * 64 + bh) * 32 + kd];
    }
    ctxT[t] = f2bf(s / den);
}

// ---------------- fused proj v3 (R11 exact): tall-M block, softmax+attend once, GEMM ----------------
// grid (32 n-blocks, 8 b), 512 threads = 8 waves. LDS = 112 KB -> 1 block/CU.
__global__ __launch_bounds__(512, 2) void proj_fused_k(
    const unsigned short* __restrict__ Wpf,   // [384][512] bf16, k = h*64+d
    const unsigned short* __restrict__ qT,    // [b][4096][256] bf16 (raw q, pre-softmax)
    const unsigned short* __restrict__ ctxT,  // [b*8+h][64 d][32 kd] bf16
    const float* __restrict__ bp,
    float* __restrict__ out)                  // [b][384][4096] f32
{
    __shared__ unsigned short Bsh[128 * 64];
    __shared__ unsigned short As[2][384 * 64];
    const int tid = threadIdx.x, lane = tid & 63, w = tid >> 6;
    const int li = lane & 15, g = lane >> 4;
    const int b = blockIdx.y, n0 = blockIdx.x * 128;

#define PROJ_STAGE(buf, s) { \
    _Pragma("unroll") \
    for (int j = 0; j < 6; ++j) { \
        int idx = j * 512 + tid; \
        int r = idx >> 3; \
        int ls = ((idx & 7) ^ (r & 7)) * 8; \
        __builtin_amdgcn_global_load_lds( \
            (const __attribute__((address_space(1))) void*)(Wpf + (long)r * 512 + (s) * 64 + ls), \
            (__attribute__((address_space(3))) void*)(As[buf] + (size_t)idx * 8), 16, 0, 0); \
    } }

    PROJ_STAGE(0, 0);

    f32x4 acc[3][8];
    #pragma unroll
    for (int i = 0; i < 3; ++i)
        #pragma unroll
        for (int j = 0; j < 8; ++j) acc[i][j] = (f32x4){0.f, 0.f, 0.f, 0.f};

    for (int s = 0; s < 8; ++s) {
        const unsigned short* cb = ctxT + ((long)b * 8 + s) * 2048;
        bf16x8 ca[4], pb;
        #pragma unroll
        for (int df = 0; df < 4; ++df)
            ca[df] = *reinterpret_cast<const bf16x8*>(cb + (df * 16 + li) * 32 + g * 8);
        {
            int n = n0 + w * 16 + li;
            bf16x8 r = *reinterpret_cast<const bf16x8*>(
                qT + (((long)b * 4096 + n) << 8) + s * 32 + g * 8);
            float f[8];
            float mx = -1e30f;
            #pragma unroll
            for (int j = 0; j < 8; ++j) { f[j] = bf2f((unsigned short)r[j]); mx = fmaxf(mx, f[j]); }
            mx = fmaxf(mx, __shfl_xor(mx, 16));
            mx = fmaxf(mx, __shfl_xor(mx, 32));
            float sm = 0.f;
            #pragma unroll
            for (int j = 0; j < 8; ++j) { f[j] = __expf(f[j] - mx); sm += f[j]; }
            sm += __shfl_xor(sm, 16);
            sm += __shfl_xor(sm, 32);
            float inv = 1.f / sm;
            #pragma unroll
            for (int j = 0; j < 8; ++j) pb[j] = (short)f2bf(f[j] * inv);
        }
        us4 bw[4];
        #pragma unroll
        for (int df = 0; df < 4; ++df) {
            f32x4 d = (f32x4){0.f, 0.f, 0.f, 0.f};
            d = __builtin_amdgcn_mfma_f32_16x16x32_bf16(ca[df], pb, d, 0, 0, 0);
            bw[df] = (us4){ f2bf(fmaxf(d.x, 0.f)), f2bf(fmaxf(d.y, 0.f)),
                            f2bf(fmaxf(d.z, 0.f)), f2bf(fmaxf(d.w, 0.f)) };
        }

        __syncthreads();

        if (s < 7) PROJ_STAGE((s + 1) & 1, s + 1);

        #pragma unroll
        for (int df = 0; df < 4; ++df) {
            int n = w * 16 + li;
            int slot = (df * 2 + (g >> 1)) ^ (n & 7);
            *reinterpret_cast<us4*>(Bsh + n * 64 + slot * 8 + (g & 1) * 4) = bw[df];
        }

        asm volatile("s_waitcnt lgkmcnt(0)\n\ts_barrier" ::: "memory");
        __builtin_amdgcn_sched_barrier(0);

        const unsigned short* Ab = As[s & 1];
        #pragma unroll
        for (int kk = 0; kk < 2; ++kk) {
            bf16x8 av[3], bv[8];
            #pragma unroll
            for (int mf = 0; mf < 3; ++mf) {
                int row = w * 48 + mf * 16 + li;
                int ps = ((kk * 4 + g) ^ (row & 7)) * 8;
                av[mf] = *reinterpret_cast<const bf16x8*>(Ab + row * 64 + ps);
            }
            #pragma unroll
            for (int nf = 0; nf < 8; ++nf) {
                int nn = nf * 16 + li;
                int ps = ((kk * 4 + g) ^ (nn & 7)) * 8;
                bv[nf] = *reinterpret_cast<const bf16x8*>(Bsh + nn * 64 + ps);
            }
            #pragma unroll
            for (int mf = 0; mf < 3; ++mf)
                #pragma unroll
                for (int nf = 0; nf < 8; ++nf)
                    acc[mf][nf] = __builtin_amdgcn_mfma_f32_16x16x32_bf16(av[mf], bv[nf], acc[mf][nf], 0, 0, 0);
        }
    }
#undef PROJ_STAGE

    #pragma unroll
    for (int mf = 0; mf < 3; ++mf) {
        int m = w * 48 + mf * 16 + g * 4;
        #pragma unroll
        for (int nf = 0; nf < 8; ++nf) {
            int n = n0 + nf * 16 + li;
            f32x4 v = acc[mf][nf];
            #pragma unroll
            for (int r = 0; r < 4; ++r)
                out[((long)b * 384 + m + r) * 4096 + n] = v[r] + bp[m + r];
        }
    }
}

// ---------------- launch ----------------
extern "C" void kernel_launch(void* const* d_in, const int* in_sizes, int n_in,
                              void* d_out, int out_size, void* d_ws, size_t ws_size,
                              hipStream_t stream) {
    (void)in_sizes; (void)n_in; (void)out_size; (void)ws_size;
    const float* x  = (const float*)d_in[0];
    const float* Wq = (const float*)d_in[1];
    const float* sq = (const float*)d_in[2];
    const float* bq = (const float*)d_in[3];
    const float* Wk = (const float*)d_in[4];
    const float* sk = (const float*)d_in[5];
    const float* bk = (const float*)d_in[6];
    const float* Wv = (const float*)d_in[7];
    const float* sv = (const float*)d_in[8];
    const float* bv = (const float*)d_in[9];
    const float* Wp = (const float*)d_in[10];
    const float* sp = (const float*)d_in[11];
    const float* bp = (const float*)d_in[12];
    float* out = (float*)d_out;

    char* wsb = (char*)d_ws;
    unsigned short* Wqkv  = (unsigned short*)(wsb);              // 786432 B
    unsigned short* Wpf   = (unsigned short*)(wsb + 786432);     // 393216 B
    float*          bqkv  = (float*)(wsb + 1179648);             // 4096 B
    unsigned short* ctxT  = (unsigned short*)(wsb + 1183744);    // 262144 B
    float*          part  = (float*)(wsb + 1445888);             // 16777216 B
    float*          psums = (float*)(wsb + 18223104);            // 262144 B
    unsigned short* qT    = (unsigned short*)(wsb + 18485248);   // 16777216 B -> 35.3 MB total

    fold_weights_k<<<2308, 256, 0, stream>>>(Wq, sq, bq, Wk, sk, bk, Wv, sv, bv, Wp, sp,
                                             Wqkv, Wpf, bqkv);
    gemm_qkv_k<<<dim3(32, 8, 8), 256, 0, stream>>>(Wqkv, x, bqkv, qT, part, psums);
    ctx_reduce_k<<<512, 256, 0, stream>>>(part, psums, ctxT);
    proj_fused_k<<<dim3(32, 8), 512, 0, stream>>>(Wpf, qT, ctxT, bp, out);
}

// Round 15
// 89.904 us; speedup vs baseline: 1.6663x; 1.0943x over previous
//
#include <hip/hip_runtime.h>

typedef __attribute__((ext_vector_type(8))) short bf16x8;
typedef __attribute__((ext_vector_type(4))) float f32x4;
typedef __attribute__((ext_vector_type(4))) unsigned short us4;

__device__ __forceinline__ unsigned short f2bf(float f) {
    unsigned int u = __builtin_bit_cast(unsigned int, f);
    u = (u + 0x7FFFu + ((u >> 16) & 1u)) >> 16;
    return (unsigned short)u;
}
__device__ __forceinline__ float bf2f(unsigned short h) {
    return __builtin_bit_cast(float, (unsigned int)h << 16);
}

// ---------------- fold BN into weights, emit bf16; per-head packed row order ----------------
__global__ __launch_bounds__(256) void fold_weights_k(
    const float* __restrict__ Wq, const float* __restrict__ sq, const float* __restrict__ bq,
    const float* __restrict__ Wk, const float* __restrict__ sk, const float* __restrict__ bk,
    const float* __restrict__ Wv, const float* __restrict__ sv, const float* __restrict__ bv,
    const float* __restrict__ Wp, const float* __restrict__ sp,
    unsigned short* __restrict__ WqkvP, unsigned short* __restrict__ Wpf, float* __restrict__ bqkvP)
{
    int i = blockIdx.x * 256 + threadIdx.x;
    if (i < 393216) {                       // WqkvP [1024][384]
        int r = i / 384, c = i - r * 384;
        int head = r >> 7, t = r & 127;
        float w, s;
        if (t < 32)      { int ch = head * 32 + t;        w = Wq[ch * 384 + c]; s = sq[ch]; }
        else if (t < 64) { int ch = head * 32 + (t - 32); w = Wk[ch * 384 + c]; s = sk[ch]; }
        else             { int ch = head * 64 + (t - 64); w = Wv[ch * 384 + c]; s = sv[ch]; }
        WqkvP[i] = f2bf(w * s);
    } else if (i < 589824) {                // Wpf [384][512]
        int j = i - 393216;
        Wpf[j] = f2bf(Wp[j] * sp[j >> 9]);
    } else if (i < 590848) {
        int r = i - 589824;
        int head = r >> 7, t = r & 127;
        bqkvP[r] = (t < 32) ? bq[head * 32 + t]
                 : (t < 64) ? bk[head * 32 + (t - 32)]
                            : bv[head * 64 + (t - 64)];
    }
}

// ---------------- fused QKV GEMM (x read directly, transpose in-LDS) + context partials ----------------
__global__ __launch_bounds__(256, 3) void gemm_qkv_k(
    const unsigned short* __restrict__ A,     // WqkvP [1024][384] head-packed
    const float* __restrict__ x,              // [b][384][4096] f32
    const float* __restrict__ bias,           // bqkvP
    unsigned short* __restrict__ q_out,       // qT [b][4096][256]
    float* __restrict__ part,                 // [32][64][64 d][32 kd]
    float* __restrict__ psums)                // [32][64][32]
{
    __shared__ unsigned short As[3 * 4096];
    __shared__ unsigned short Bs[3 * 4096];
    const int tid = threadIdx.x;
    const int lane = tid & 63;
    const int w = tid >> 6, wr = w >> 1, wc = w & 1;
    const int li = lane & 15, g = lane >> 4;
    const int b = blockIdx.z, head = blockIdx.y, chunk = blockIdx.x;
    const int n0 = chunk * 128, m0 = head * 128;
    const float* xb = x + (long)b * 384 * 4096 + n0 + 2 * lane;

    const int i0 = tid, i1 = tid + 256;
    const int p0 = i0 >> 3, v0 = (i0 & 7) ^ (p0 & 7);
    const int p1 = i1 >> 3, v1 = (i1 & 7) ^ (p1 & 7);
    const long aro0 = (long)m0 * 384 + (long)(p0 * 2 + (v0 >> 2)) * 384 + (v0 & 3) * 8;
    const long aro1 = (long)m0 * 384 + (long)(p1 * 2 + (v1 >> 2)) * 384 + (v1 & 3) * 8;

#define ISSUE_A(kt) { const int _bf = (kt) % 3; const int _k0 = (kt) * 32; \
    __builtin_amdgcn_global_load_lds( \
        (const __attribute__((address_space(1))) void*)(A + aro0 + _k0), \
        (__attribute__((address_space(3))) void*)(As + _bf * 4096 + (size_t)i0 * 8), 16, 0, 0); \
    __builtin_amdgcn_global_load_lds( \
        (const __attribute__((address_space(1))) void*)(A + aro1 + _k0), \
        (__attribute__((address_space(3))) void*)(As + _bf * 4096 + (size_t)i1 * 8), 16, 0, 0); }

#define ISSUE_B(kt, breg) { const int _k0 = (kt) * 32 + w * 8; \
    _Pragma("unroll") \
    for (int j = 0; j < 8; ++j) \
        breg[j] = *reinterpret_cast<const float2*>(xb + (long)(_k0 + j) * 4096); }

// pack via v_cvt_pk_bf16_f32 (2 f32 -> 1 u32 of 2xbf16, elem order lo=src0)
#define WRITE_B(breg, _bf) { \
    unsigned int pw0[4], pw1[4]; \
    _Pragma("unroll") \
    for (int j = 0; j < 4; ++j) { \
        asm("v_cvt_pk_bf16_f32 %0, %1, %2" : "=v"(pw0[j]) : "v"(breg[2*j].x), "v"(breg[2*j+1].x)); \
        asm("v_cvt_pk_bf16_f32 %0, %1, %2" : "=v"(pw1[j]) : "v"(breg[2*j].y), "v"(breg[2*j+1].y)); \
    } \
    uint4 q0 = {pw0[0], pw0[1], pw0[2], pw0[3]}; \
    uint4 q1 = {pw1[0], pw1[1], pw1[2], pw1[3]}; \
    int s0 = w ^ (lane & 7), s1 = (4 + w) ^ (lane & 7); \
    *reinterpret_cast<uint4*>(Bs + (_bf) * 4096 + lane * 64 + s0 * 8) = q0; \
    *reinterpret_cast<uint4*>(Bs + (_bf) * 4096 + lane * 64 + s1 * 8) = q1; }

    float2 bregA[8], bregB[8];
    ISSUE_A(0); ISSUE_B(0, bregA);
    ISSUE_A(1); ISSUE_B(1, bregB);
    WRITE_B(bregA, 0);
    asm volatile("s_waitcnt vmcnt(10) lgkmcnt(0)\n\ts_barrier" ::: "memory");
    __builtin_amdgcn_sched_barrier(0);

    f32x4 acc[4][4];
    #pragma unroll
    for (int i = 0; i < 4; ++i)
        #pragma unroll
        for (int j = 0; j < 4; ++j) acc[i][j] = (f32x4){0.f, 0.f, 0.f, 0.f};

    #pragma unroll
    for (int kt = 0; kt < 12; ++kt) {
        const unsigned short* Ab = As + (kt % 3) * 4096;
        const unsigned short* Bl = Bs + (kt % 3) * 4096;

        bf16x8 av[4], bv[4];
        #pragma unroll
        for (int mf = 0; mf < 4; ++mf) {
            int r = wr * 64 + mf * 16 + li;
            int p = r >> 1;
            int slot = (((r & 1) * 4 + g) ^ (p & 7));
            av[mf] = *reinterpret_cast<const bf16x8*>(Ab + p * 64 + slot * 8);
        }
        #pragma unroll
        for (int nf = 0; nf < 4; ++nf) {
            int r = wc * 64 + nf * 16 + li;
            int p = r >> 1;
            int slot = (((r & 1) * 4 + g) ^ (p & 7));
            bv[nf] = *reinterpret_cast<const bf16x8*>(Bl + p * 64 + slot * 8);
        }
        if (kt < 10) {
            ISSUE_A(kt + 2);
            if (kt & 1) { ISSUE_B(kt + 2, bregB) }
            else        { ISSUE_B(kt + 2, bregA) }
        }
        __builtin_amdgcn_s_setprio(1);
        #pragma unroll
        for (int mf = 0; mf < 4; ++mf)
            #pragma unroll
            for (int nf = 0; nf < 4; ++nf)
                acc[mf][nf] = __builtin_amdgcn_mfma_f32_16x16x32_bf16(av[mf], bv[nf], acc[mf][nf], 0, 0, 0);
        __builtin_amdgcn_s_setprio(0);
        if (kt < 11) {
            if (kt & 1) { WRITE_B(bregA, (kt + 1) % 3) }
            else        { WRITE_B(bregB, (kt + 1) % 3) }
            asm volatile("s_waitcnt lgkmcnt(0)\n\ts_barrier" ::: "memory");
            __builtin_amdgcn_sched_barrier(0);
        }
    }
#undef ISSUE_A
#undef ISSUE_B
#undef WRITE_B

    __syncthreads();

    unsigned short* Ksh = As;
    unsigned short* Vsh = As + 4096;
    float* psl = reinterpret_cast<float*>(Bs);   // [2][32]

    if (wr == 0) {
        #pragma unroll
        for (int mf = 0; mf < 2; ++mf) {
            int ml = mf * 16 + g * 4;
            #pragma unroll
            for (int nf = 0; nf < 4; ++nf) {
                int n = n0 + wc * 64 + nf * 16 + li;
                f32x4 v = acc[mf][nf];
                us4 o = { f2bf(v.x + bias[m0 + ml]),     f2bf(v.y + bias[m0 + ml + 1]),
                          f2bf(v.z + bias[m0 + ml + 2]), f2bf(v.w + bias[m0 + ml + 3]) };
                *reinterpret_cast<us4*>(q_out + (((long)b * 4096 + n) << 8) + head * 32 + ml) = o;
            }
        }
        float rs[2][4] = {{0.f,0.f,0.f,0.f},{0.f,0.f,0.f,0.f}};
        #pragma unroll
        for (int mm = 0; mm < 2; ++mm) {
            #pragma unroll
            for (int nf = 0; nf < 4; ++nf) {
                int nl = wc * 64 + nf * 16 + li;
                f32x4 v = acc[mm + 2][nf];
                #pragma unroll
                for (int r = 0; r < 4; ++r) {
                    int kd = mm * 16 + g * 4 + r;
                    float e = __expf(v[r] + bias[m0 + 32 + kd]);
                    rs[mm][r] += e;
                    Ksh[kd * 128 + ((((nl >> 3) ^ (kd & 7)) << 3) | (nl & 7))] = f2bf(e);
                }
            }
        }
        #pragma unroll
        for (int mm = 0; mm < 2; ++mm)
            #pragma unroll
            for (int r = 0; r < 4; ++r) {
                float s = rs[mm][r];
                s += __shfl_xor(s, 1); s += __shfl_xor(s, 2);
                s += __shfl_xor(s, 4); s += __shfl_xor(s, 8);
                if (li == 0) psl[wc * 32 + mm * 16 + g * 4 + r] = s;
            }
    } else {
        #pragma unroll
        for (int mf = 0; mf < 4; ++mf) {
            #pragma unroll
            for (int nf = 0; nf < 4; ++nf) {
                int nl = wc * 64 + nf * 16 + li;
                f32x4 v = acc[mf][nf];
                #pragma unroll
                for (int r = 0; r < 4; ++r) {
                    int d = mf * 16 + g * 4 + r;
                    Vsh[d * 128 + ((((nl >> 3) ^ (d & 7)) << 3) | (nl & 7))] =
                        f2bf(v[r] + bias[m0 + 64 + d]);
                }
            }
        }
    }
    __syncthreads();

    // ---- mini-GEMM: ctx_part[d][kd] over n=128; wave w owns d-cols w*16..+16
    f32x4 c2[2] = {(f32x4){0.f,0.f,0.f,0.f}, (f32x4){0.f,0.f,0.f,0.f}};
    #pragma unroll
    for (int ks = 0; ks < 4; ++ks) {
        int rd = w * 16 + li;
        bf16x8 a0 = *reinterpret_cast<const bf16x8*>(Ksh + li * 128        + ((((ks * 4 + g) ^ (li & 7)) << 3)));
        bf16x8 a1 = *reinterpret_cast<const bf16x8*>(Ksh + (16 + li) * 128 + ((((ks * 4 + g) ^ ((16 + li) & 7)) << 3)));
        bf16x8 bb = *reinterpret_cast<const bf16x8*>(Vsh + rd * 128        + ((((ks * 4 + g) ^ (rd & 7)) << 3)));
        c2[0] = __builtin_amdgcn_mfma_f32_16x16x32_bf16(a0, bb, c2[0], 0, 0, 0);
        c2[1] = __builtin_amdgcn_mfma_f32_16x16x32_bf16(a1, bb, c2[1], 0, 0, 0);
    }
    const int bh = b * 8 + head;
    const long pbase = ((long)chunk * 64 + bh) * 2048;
    // store [d][kd]: c2[mm] holds 4 consecutive kd (mm*16+g*4+r) for d = w*16+li
    #pragma unroll
    for (int mm = 0; mm < 2; ++mm)
        *reinterpret_cast<f32x4*>(&part[pbase + (long)(w * 16 + li) * 32 + mm * 16 + g * 4]) = c2[mm];
    if (tid < 32)
        psums[((long)chunk * 64 + bh) * 32 + tid] = psl[tid] + psl[32 + tid];
}

// ---------------- reduce 32 chunks, normalize -> ctxT[bh][d][kd] bf16 (coalesced reads) ----------------
__global__ __launch_bounds__(256) void ctx_reduce_k(const float* __restrict__ part,
                                                    const float* __restrict__ psums,
                                                    unsigned short* __restrict__ ctxT)
{
    int t = blockIdx.x * 256 + threadIdx.x;   // < 131072
    int bh = t >> 11, i = t & 2047;           // i = d*32 + kd
    int kd = i & 31;
    float s = 0.f, den = 0.f;
    #pragma unroll
    for (int c = 0; c < 32; ++c) {
        s   += part[((long)c * 64 + bh) * 2048 + i];
        den += psums[((long)c * 64 + bh) * 32 + kd];
    }
    ctxT[t] = f2bf(s / den);
}

// ---------------- fused proj v3: tall-M block, softmax+attend once, GEMM ----------------
// grid (32 n-blocks, 8 b), 512 threads = 8 waves. LDS = 112 KB -> 1 block/CU.
__global__ __launch_bounds__(512, 2) void proj_fused_k(
    const unsigned short* __restrict__ Wpf,   // [384][512] bf16, k = h*64+d
    const unsigned short* __restrict__ qT,    // [b][4096][256] bf16 (raw q, pre-softmax)
    const unsigned short* __restrict__ ctxT,  // [b*8+h][64 d][32 kd] bf16
    const float* __restrict__ bp,
    float* __restrict__ out)                  // [b][384][4096] f32
{
    __shared__ unsigned short Bsh[128 * 64];
    __shared__ unsigned short As[2][384 * 64];
    const int tid = threadIdx.x, lane = tid & 63, w = tid >> 6;
    const int li = lane & 15, g = lane >> 4;
    const int b = blockIdx.y, n0 = blockIdx.x * 128;

#define PROJ_STAGE(buf, s) { \
    _Pragma("unroll") \
    for (int j = 0; j < 6; ++j) { \
        int idx = j * 512 + tid; \
        int r = idx >> 3; \
        int ls = ((idx & 7) ^ (r & 7)) * 8; \
        __builtin_amdgcn_global_load_lds( \
            (const __attribute__((address_space(1))) void*)(Wpf + (long)r * 512 + (s) * 64 + ls), \
            (__attribute__((address_space(3))) void*)(As[buf] + (size_t)idx * 8), 16, 0, 0); \
    } }

    PROJ_STAGE(0, 0);

    f32x4 acc[3][8];
    #pragma unroll
    for (int i = 0; i < 3; ++i)
        #pragma unroll
        for (int j = 0; j < 8; ++j) acc[i][j] = (f32x4){0.f, 0.f, 0.f, 0.f};

    for (int s = 0; s < 8; ++s) {
        const unsigned short* cb = ctxT + ((long)b * 8 + s) * 2048;
        bf16x8 ca[4], pb;
        #pragma unroll
        for (int df = 0; df < 4; ++df)
            ca[df] = *reinterpret_cast<const bf16x8*>(cb + (df * 16 + li) * 32 + g * 8);
        {
            int n = n0 + w * 16 + li;
            bf16x8 r = *reinterpret_cast<const bf16x8*>(
                qT + (((long)b * 4096 + n) << 8) + s * 32 + g * 8);
            float f[8];
            float mx = -1e30f;
            #pragma unroll
            for (int j = 0; j < 8; ++j) { f[j] = bf2f((unsigned short)r[j]); mx = fmaxf(mx, f[j]); }
            mx = fmaxf(mx, __shfl_xor(mx, 16));
            mx = fmaxf(mx, __shfl_xor(mx, 32));
            float sm = 0.f;
            #pragma unroll
            for (int j = 0; j < 8; ++j) { f[j] = __expf(f[j] - mx); sm += f[j]; }
            sm += __shfl_xor(sm, 16);
            sm += __shfl_xor(sm, 32);
            float inv = 1.f / sm;
            #pragma unroll
            for (int j = 0; j < 8; ++j) pb[j] = (short)f2bf(f[j] * inv);
        }
        us4 bw[4];
        #pragma unroll
        for (int df = 0; df < 4; ++df) {
            f32x4 d = (f32x4){0.f, 0.f, 0.f, 0.f};
            d = __builtin_amdgcn_mfma_f32_16x16x32_bf16(ca[df], pb, d, 0, 0, 0);
            bw[df] = (us4){ f2bf(fmaxf(d.x, 0.f)), f2bf(fmaxf(d.y, 0.f)),
                            f2bf(fmaxf(d.z, 0.f)), f2bf(fmaxf(d.w, 0.f)) };
        }

        __syncthreads();

        if (s < 7) PROJ_STAGE((s + 1) & 1, s + 1);

        #pragma unroll
        for (int df = 0; df < 4; ++df) {
            int n = w * 16 + li;
            int slot = (df * 2 + (g >> 1)) ^ (n & 7);
            *reinterpret_cast<us4*>(Bsh + n * 64 + slot * 8 + (g & 1) * 4) = bw[df];
        }

        asm volatile("s_waitcnt lgkmcnt(0)\n\ts_barrier" ::: "memory");
        __builtin_amdgcn_sched_barrier(0);

        const unsigned short* Ab = As[s & 1];
        #pragma unroll
        for (int kk = 0; kk < 2; ++kk) {
            bf16x8 av[3], bv[8];
            #pragma unroll
            for (int mf = 0; mf < 3; ++mf) {
                int row = w * 48 + mf * 16 + li;
                int ps = ((kk * 4 + g) ^ (row & 7)) * 8;
                av[mf] = *reinterpret_cast<const bf16x8*>(Ab + row * 64 + ps);
            }
            #pragma unroll
            for (int nf = 0; nf < 8; ++nf) {
                int nn = nf * 16 + li;
                int ps = ((kk * 4 + g) ^ (nn & 7)) * 8;
                bv[nf] = *reinterpret_cast<const bf16x8*>(Bsh + nn * 64 + ps);
            }
            #pragma unroll
            for (int mf = 0; mf < 3; ++mf)
                #pragma unroll
                for (int nf = 0; nf < 8; ++nf)
                    acc[mf][nf] = __builtin_amdgcn_mfma_f32_16x16x32_bf16(av[mf], bv[nf], acc[mf][nf], 0, 0, 0);
        }
    }
#undef PROJ_STAGE

    #pragma unroll
    for (int mf = 0; mf < 3; ++mf) {
        int m = w * 48 + mf * 16 + g * 4;
        #pragma unroll
        for (int nf = 0; nf < 8; ++nf) {
            int n = n0 + nf * 16 + li;
            f32x4 v = acc[mf][nf];
            #pragma unroll
            for (int r = 0; r < 4; ++r)
                out[((long)b * 384 + m + r) * 4096 + n] = v[r] + bp[m + r];
        }
    }
}

// ---------------- launch ----------------
extern "C" void kernel_launch(void* const* d_in, const int* in_sizes, int n_in,
                              void* d_out, int out_size, void* d_ws, size_t ws_size,
                              hipStream_t stream) {
    (void)in_sizes; (void)n_in; (void)out_size; (void)ws_size;
    const float* x  = (const float*)d_in[0];
    const float* Wq = (const float*)d_in[1];
    const float* sq = (const float*)d_in[2];
    const float* bq = (const float*)d_in[3];
    const float* Wk = (const float*)d_in[4];
    const float* sk = (const float*)d_in[5];
    const float* bk = (const float*)d_in[6];
    const float* Wv = (const float*)d_in[7];
    const float* sv = (const float*)d_in[8];
    const float* bv = (const float*)d_in[9];
    const float* Wp = (const float*)d_in[10];
    const float* sp = (const float*)d_in[11];
    const float* bp = (const float*)d_in[12];
    float* out = (float*)d_out;

    char* wsb = (char*)d_ws;
    unsigned short* Wqkv  = (unsigned short*)(wsb);              // 786432 B
    unsigned short* Wpf   = (unsigned short*)(wsb + 786432);     // 393216 B
    float*          bqkv  = (float*)(wsb + 1179648);             // 4096 B
    unsigned short* ctxT  = (unsigned short*)(wsb + 1183744);    // 262144 B
    float*          part  = (float*)(wsb + 1445888);             // 16777216 B
    float*          psums = (float*)(wsb + 18223104);            // 262144 B
    unsigned short* qT    = (unsigned short*)(wsb + 18485248);   // 16777216 B -> 35.3 MB total

    fold_weights_k<<<2308, 256, 0, stream>>>(Wq, sq, bq, Wk, sk, bk, Wv, sv, bv, Wp, sp,
                                             Wqkv, Wpf, bqkv);
    gemm_qkv_k<<<dim3(32, 8, 8), 256, 0, stream>>>(Wqkv, x, bqkv, qT, part, psums);
    ctx_reduce_k<<<512, 256, 0, stream>>>(part, psums, ctxT);
    proj_fused_k<<<dim3(32, 8), 512, 0, stream>>>(Wpf, qT, ctxT, bp, out);
}

// Round 16
// 89.249 us; speedup vs baseline: 1.6785x; 1.0073x over previous
//
#include <hip/hip_runtime.h>

typedef __attribute__((ext_vector_type(8))) short bf16x8;
typedef __attribute__((ext_vector_type(4))) float f32x4;
typedef __attribute__((ext_vector_type(4))) unsigned short us4;

__device__ __forceinline__ unsigned short f2bf(float f) {
    unsigned int u = __builtin_bit_cast(unsigned int, f);
    u = (u + 0x7FFFu + ((u >> 16) & 1u)) >> 16;
    return (unsigned short)u;
}
__device__ __forceinline__ float bf2f(unsigned short h) {
    return __builtin_bit_cast(float, (unsigned int)h << 16);
}

// ---------------- fold BN into weights, emit bf16; per-head packed row order ----------------
__global__ __launch_bounds__(256) void fold_weights_k(
    const float* __restrict__ Wq, const float* __restrict__ sq, const float* __restrict__ bq,
    const float* __restrict__ Wk, const float* __restrict__ sk, const float* __restrict__ bk,
    const float* __restrict__ Wv, const float* __restrict__ sv, const float* __restrict__ bv,
    const float* __restrict__ Wp, const float* __restrict__ sp,
    unsigned short* __restrict__ WqkvP, unsigned short* __restrict__ Wpf, float* __restrict__ bqkvP)
{
    int i = blockIdx.x * 256 + threadIdx.x;
    if (i < 393216) {                       // WqkvP [1024][384]
        int r = i / 384, c = i - r * 384;
        int head = r >> 7, t = r & 127;
        float w, s;
        if (t < 32)      { int ch = head * 32 + t;        w = Wq[ch * 384 + c]; s = sq[ch]; }
        else if (t < 64) { int ch = head * 32 + (t - 32); w = Wk[ch * 384 + c]; s = sk[ch]; }
        else             { int ch = head * 64 + (t - 64); w = Wv[ch * 384 + c]; s = sv[ch]; }
        WqkvP[i] = f2bf(w * s);
    } else if (i < 589824) {                // Wpf [384][512]
        int j = i - 393216;
        Wpf[j] = f2bf(Wp[j] * sp[j >> 9]);
    } else if (i < 590848) {
        int r = i - 589824;
        int head = r >> 7, t = r & 127;
        bqkvP[r] = (t < 32) ? bq[head * 32 + t]
                 : (t < 64) ? bk[head * 32 + (t - 32)]
                            : bv[head * 64 + (t - 64)];
    }
}

// ---------------- fused QKV GEMM (x read directly, transpose in-LDS) + context partials ----------------
// Single barrier per K-tile: top wait = vmcnt(4)+lgkmcnt(0)+barrier covers (1) A gload_lds
// landed, (2) prior tile's WRITE_B ds_writes visible, (3) buffer-reuse safety (readers of
// buf (kt+1)%3 finished at tile kt-2, two barriers ago).
__global__ __launch_bounds__(256, 3) void gemm_qkv_k(
    const unsigned short* __restrict__ A,     // WqkvP [1024][384] head-packed
    const float* __restrict__ x,              // [b][384][4096] f32
    const float* __restrict__ bias,           // bqkvP
    unsigned short* __restrict__ q_out,       // qT [b][4096][256]
    float* __restrict__ part,                 // [32][64][64 d][32 kd]
    float* __restrict__ psums)                // [32][64][32]
{
    __shared__ unsigned short As[3 * 4096];
    __shared__ unsigned short Bs[3 * 4096];
    const int tid = threadIdx.x;
    const int lane = tid & 63;
    const int w = tid >> 6, wr = w >> 1, wc = w & 1;
    const int li = lane & 15, g = lane >> 4;
    const int b = blockIdx.z, head = blockIdx.y, chunk = blockIdx.x;
    const int n0 = chunk * 128, m0 = head * 128;
    const float* xb = x + (long)b * 384 * 4096 + n0 + 2 * lane;

    const int i0 = tid, i1 = tid + 256;
    const int p0 = i0 >> 3, v0 = (i0 & 7) ^ (p0 & 7);
    const int p1 = i1 >> 3, v1 = (i1 & 7) ^ (p1 & 7);
    const long aro0 = (long)m0 * 384 + (long)(p0 * 2 + (v0 >> 2)) * 384 + (v0 & 3) * 8;
    const long aro1 = (long)m0 * 384 + (long)(p1 * 2 + (v1 >> 2)) * 384 + (v1 & 3) * 8;

#define ISSUE_A(kt) { const int _bf = (kt) % 3; const int _k0 = (kt) * 32; \
    __builtin_amdgcn_global_load_lds( \
        (const __attribute__((address_space(1))) void*)(A + aro0 + _k0), \
        (__attribute__((address_space(3))) void*)(As + _bf * 4096 + (size_t)i0 * 8), 16, 0, 0); \
    __builtin_amdgcn_global_load_lds( \
        (const __attribute__((address_space(1))) void*)(A + aro1 + _k0), \
        (__attribute__((address_space(3))) void*)(As + _bf * 4096 + (size_t)i1 * 8), 16, 0, 0); }

#define ISSUE_B(kt, breg) { const int _k0 = (kt) * 32 + w * 8; \
    _Pragma("unroll") \
    for (int j = 0; j < 8; ++j) \
        breg[j] = *reinterpret_cast<const float2*>(xb + (long)(_k0 + j) * 4096); }

// pack via v_cvt_pk_bf16_f32 (2 f32 -> 1 u32 of 2xbf16, elem order lo=src0)
#define WRITE_B(breg, _bf) { \
    unsigned int pw0[4], pw1[4]; \
    _Pragma("unroll") \
    for (int j = 0; j < 4; ++j) { \
        asm("v_cvt_pk_bf16_f32 %0, %1, %2" : "=v"(pw0[j]) : "v"(breg[2*j].x), "v"(breg[2*j+1].x)); \
        asm("v_cvt_pk_bf16_f32 %0, %1, %2" : "=v"(pw1[j]) : "v"(breg[2*j].y), "v"(breg[2*j+1].y)); \
    } \
    uint4 q0 = {pw0[0], pw0[1], pw0[2], pw0[3]}; \
    uint4 q1 = {pw1[0], pw1[1], pw1[2], pw1[3]}; \
    int s0 = w ^ (lane & 7), s1 = (4 + w) ^ (lane & 7); \
    *reinterpret_cast<uint4*>(Bs + (_bf) * 4096 + lane * 64 + s0 * 8) = q0; \
    *reinterpret_cast<uint4*>(Bs + (_bf) * 4096 + lane * 64 + s1 * 8) = q1; }

    float2 bregA[8], bregB[8];
    ISSUE_A(0); ISSUE_B(0, bregA);
    ISSUE_A(1); ISSUE_B(1, bregB);
    WRITE_B(bregA, 0);

    f32x4 acc[4][4];
    #pragma unroll
    for (int i = 0; i < 4; ++i)
        #pragma unroll
        for (int j = 0; j < 4; ++j) acc[i][j] = (f32x4){0.f, 0.f, 0.f, 0.f};

    #pragma unroll
    for (int kt = 0; kt < 12; ++kt) {
        // single per-tile sync: A(kt) landed (vmcnt), WRITE_B(kt) visible (lgkm), all waves aligned
        if (kt < 11) asm volatile("s_waitcnt vmcnt(4) lgkmcnt(0)\n\ts_barrier" ::: "memory");
        else         asm volatile("s_waitcnt vmcnt(0) lgkmcnt(0)\n\ts_barrier" ::: "memory");
        __builtin_amdgcn_sched_barrier(0);

        const unsigned short* Ab = As + (kt % 3) * 4096;
        const unsigned short* Bl = Bs + (kt % 3) * 4096;

        bf16x8 av[4], bv[4];
        #pragma unroll
        for (int mf = 0; mf < 4; ++mf) {
            int r = wr * 64 + mf * 16 + li;
            int p = r >> 1;
            int slot = (((r & 1) * 4 + g) ^ (p & 7));
            av[mf] = *reinterpret_cast<const bf16x8*>(Ab + p * 64 + slot * 8);
        }
        #pragma unroll
        for (int nf = 0; nf < 4; ++nf) {
            int r = wc * 64 + nf * 16 + li;
            int p = r >> 1;
            int slot = (((r & 1) * 4 + g) ^ (p & 7));
            bv[nf] = *reinterpret_cast<const bf16x8*>(Bl + p * 64 + slot * 8);
        }
        if (kt < 10) {
            ISSUE_A(kt + 2);
            if (kt & 1) { ISSUE_B(kt + 2, bregB) }
            else        { ISSUE_B(kt + 2, bregA) }
        }
        __builtin_amdgcn_s_setprio(1);
        #pragma unroll
        for (int mf = 0; mf < 4; ++mf)
            #pragma unroll
            for (int nf = 0; nf < 4; ++nf)
                acc[mf][nf] = __builtin_amdgcn_mfma_f32_16x16x32_bf16(av[mf], bv[nf], acc[mf][nf], 0, 0, 0);
        __builtin_amdgcn_s_setprio(0);
        if (kt < 11) {
            // write tile kt+1's B into buf (kt+1)%3 — its previous readers (tile kt-2)
            // finished before tile kt-1's barrier; visibility ensured by next top barrier.
            if (kt & 1) { WRITE_B(bregA, (kt + 1) % 3) }
            else        { WRITE_B(bregB, (kt + 1) % 3) }
        }
    }
#undef ISSUE_A
#undef ISSUE_B
#undef WRITE_B

    __syncthreads();

    unsigned short* Ksh = As;
    unsigned short* Vsh = As + 4096;
    float* psl = reinterpret_cast<float*>(Bs);   // [2][32]

    if (wr == 0) {
        #pragma unroll
        for (int mf = 0; mf < 2; ++mf) {
            int ml = mf * 16 + g * 4;
            #pragma unroll
            for (int nf = 0; nf < 4; ++nf) {
                int n = n0 + wc * 64 + nf * 16 + li;
                f32x4 v = acc[mf][nf];
                us4 o = { f2bf(v.x + bias[m0 + ml]),     f2bf(v.y + bias[m0 + ml + 1]),
                          f2bf(v.z + bias[m0 + ml + 2]), f2bf(v.w + bias[m0 + ml + 3]) };
                *reinterpret_cast<us4*>(q_out + (((long)b * 4096 + n) << 8) + head * 32 + ml) = o;
            }
        }
        float rs[2][4] = {{0.f,0.f,0.f,0.f},{0.f,0.f,0.f,0.f}};
        #pragma unroll
        for (int mm = 0; mm < 2; ++mm) {
            #pragma unroll
            for (int nf = 0; nf < 4; ++nf) {
                int nl = wc * 64 + nf * 16 + li;
                f32x4 v = acc[mm + 2][nf];
                #pragma unroll
                for (int r = 0; r < 4; ++r) {
                    int kd = mm * 16 + g * 4 + r;
                    float e = __expf(v[r] + bias[m0 + 32 + kd]);
                    rs[mm][r] += e;
                    Ksh[kd * 128 + ((((nl >> 3) ^ (kd & 7)) << 3) | (nl & 7))] = f2bf(e);
                }
            }
        }
        #pragma unroll
        for (int mm = 0; mm < 2; ++mm)
            #pragma unroll
            for (int r = 0; r < 4; ++r) {
                float s = rs[mm][r];
                s += __shfl_xor(s, 1); s += __shfl_xor(s, 2);
                s += __shfl_xor(s, 4); s += __shfl_xor(s, 8);
                if (li == 0) psl[wc * 32 + mm * 16 + g * 4 + r] = s;
            }
    } else {
        #pragma unroll
        for (int mf = 0; mf < 4; ++mf) {
            #pragma unroll
            for (int nf = 0; nf < 4; ++nf) {
                int nl = wc * 64 + nf * 16 + li;
                f32x4 v = acc[mf][nf];
                #pragma unroll
                for (int r = 0; r < 4; ++r) {
                    int d = mf * 16 + g * 4 + r;
                    Vsh[d * 128 + ((((nl >> 3) ^ (d & 7)) << 3) | (nl & 7))] =
                        f2bf(v[r] + bias[m0 + 64 + d]);
                }
            }
        }
    }
    __syncthreads();

    // ---- mini-GEMM: ctx_part[d][kd] over n=128; wave w owns d-cols w*16..+16
    f32x4 c2[2] = {(f32x4){0.f,0.f,0.f,0.f}, (f32x4){0.f,0.f,0.f,0.f}};
    #pragma unroll
    for (int ks = 0; ks < 4; ++ks) {
        int rd = w * 16 + li;
        bf16x8 a0 = *reinterpret_cast<const bf16x8*>(Ksh + li * 128        + ((((ks * 4 + g) ^ (li & 7)) << 3)));
        bf16x8 a1 = *reinterpret_cast<const bf16x8*>(Ksh + (16 + li) * 128 + ((((ks * 4 + g) ^ ((16 + li) & 7)) << 3)));
        bf16x8 bb = *reinterpret_cast<const bf16x8*>(Vsh + rd * 128        + ((((ks * 4 + g) ^ (rd & 7)) << 3)));
        c2[0] = __builtin_amdgcn_mfma_f32_16x16x32_bf16(a0, bb, c2[0], 0, 0, 0);
        c2[1] = __builtin_amdgcn_mfma_f32_16x16x32_bf16(a1, bb, c2[1], 0, 0, 0);
    }
    const int bh = b * 8 + head;
    const long pbase = ((long)chunk * 64 + bh) * 2048;
    // store [d][kd]: c2[mm] holds 4 consecutive kd (mm*16+g*4+r) for d = w*16+li
    #pragma unroll
    for (int mm = 0; mm < 2; ++mm)
        *reinterpret_cast<f32x4*>(&part[pbase + (long)(w * 16 + li) * 32 + mm * 16 + g * 4]) = c2[mm];
    if (tid < 32)
        psums[((long)chunk * 64 + bh) * 32 + tid] = psl[tid] + psl[32 + tid];
}

// ---------------- reduce 32 chunks, normalize -> ctxT[bh][d][kd] bf16 (coalesced reads) ----------------
__global__ __launch_bounds__(256) void ctx_reduce_k(const float* __restrict__ part,
                                                    const float* __restrict__ psums,
                                                    unsigned short* __restrict__ ctxT)
{
    int t = blockIdx.x * 256 + threadIdx.x;   // < 131072
    int bh = t >> 11, i = t & 2047;           // i = d*32 + kd
    int kd = i & 31;
    float s = 0.f, den = 0.f;
    #pragma unroll
    for (int c = 0; c < 32; ++c) {
        s   += part[((long)c * 64 + bh) * 2048 + i];
        den += psums[((long)c * 64 + bh) * 32 + kd];
    }
    ctxT[t] = f2bf(s / den);
}

// ---------------- fused proj v3: tall-M block, softmax+attend once, GEMM ----------------
// grid (32 n-blocks, 8 b), 512 threads = 8 waves. LDS = 112 KB -> 1 block/CU.
__global__ __launch_bounds__(512, 2) void proj_fused_k(
    const unsigned short* __restrict__ Wpf,   // [384][512] bf16, k = h*64+d
    const unsigned short* __restrict__ qT,    // [b][4096][256] bf16 (raw q, pre-softmax)
    const unsigned short* __restrict__ ctxT,  // [b*8+h][64 d][32 kd] bf16
    const float* __restrict__ bp,
    float* __restrict__ out)                  // [b][384][4096] f32
{
    __shared__ unsigned short Bsh[128 * 64];
    __shared__ unsigned short As[2][384 * 64];
    const int tid = threadIdx.x, lane = tid & 63, w = tid >> 6;
    const int li = lane & 15, g = lane >> 4;
    const int b = blockIdx.y, n0 = blockIdx.x * 128;

#define PROJ_STAGE(buf, s) { \
    _Pragma("unroll") \
    for (int j = 0; j < 6; ++j) { \
        int idx = j * 512 + tid; \
        int r = idx >> 3; \
        int ls = ((idx & 7) ^ (r & 7)) * 8; \
        __builtin_amdgcn_global_load_lds( \
            (const __attribute__((address_space(1))) void*)(Wpf + (long)r * 512 + (s) * 64 + ls), \
            (__attribute__((address_space(3))) void*)(As[buf] + (size_t)idx * 8), 16, 0, 0); \
    } }

    PROJ_STAGE(0, 0);

    f32x4 acc[3][8];
    #pragma unroll
    for (int i = 0; i < 3; ++i)
        #pragma unroll
        for (int j = 0; j < 8; ++j) acc[i][j] = (f32x4){0.f, 0.f, 0.f, 0.f};

    for (int s = 0; s < 8; ++s) {
        const unsigned short* cb = ctxT + ((long)b * 8 + s) * 2048;
        bf16x8 ca[4], pb;
        #pragma unroll
        for (int df = 0; df < 4; ++df)
            ca[df] = *reinterpret_cast<const bf16x8*>(cb + (df * 16 + li) * 32 + g * 8);
        {
            int n = n0 + w * 16 + li;
            bf16x8 r = *reinterpret_cast<const bf16x8*>(
                qT + (((long)b * 4096 + n) << 8) + s * 32 + g * 8);
            float f[8];
            float mx = -1e30f;
            #pragma unroll
            for (int j = 0; j < 8; ++j) { f[j] = bf2f((unsigned short)r[j]); mx = fmaxf(mx, f[j]); }
            mx = fmaxf(mx, __shfl_xor(mx, 16));
            mx = fmaxf(mx, __shfl_xor(mx, 32));
            float sm = 0.f;
            #pragma unroll
            for (int j = 0; j < 8; ++j) { f[j] = __expf(f[j] - mx); sm += f[j]; }
            sm += __shfl_xor(sm, 16);
            sm += __shfl_xor(sm, 32);
            float inv = 1.f / sm;
            #pragma unroll
            for (int j = 0; j < 8; ++j) pb[j] = (short)f2bf(f[j] * inv);
        }
        us4 bw[4];
        #pragma unroll
        for (int df = 0; df < 4; ++df) {
            f32x4 d = (f32x4){0.f, 0.f, 0.f, 0.f};
            d = __builtin_amdgcn_mfma_f32_16x16x32_bf16(ca[df], pb, d, 0, 0, 0);
            bw[df] = (us4){ f2bf(fmaxf(d.x, 0.f)), f2bf(fmaxf(d.y, 0.f)),
                            f2bf(fmaxf(d.z, 0.f)), f2bf(fmaxf(d.w, 0.f)) };
        }

        __syncthreads();

        if (s < 7) PROJ_STAGE((s + 1) & 1, s + 1);

        #pragma unroll
        for (int df = 0; df < 4; ++df) {
            int n = w * 16 + li;
            int slot = (df * 2 + (g >> 1)) ^ (n & 7);
            *reinterpret_cast<us4*>(Bsh + n * 64 + slot * 8 + (g & 1) * 4) = bw[df];
        }

        asm volatile("s_waitcnt lgkmcnt(0)\n\ts_barrier" ::: "memory");
        __builtin_amdgcn_sched_barrier(0);

        const unsigned short* Ab = As[s & 1];
        #pragma unroll
        for (int kk = 0; kk < 2; ++kk) {
            bf16x8 av[3], bv[8];
            #pragma unroll
            for (int mf = 0; mf < 3; ++mf) {
                int row = w * 48 + mf * 16 + li;
                int ps = ((kk * 4 + g) ^ (row & 7)) * 8;
                av[mf] = *reinterpret_cast<const bf16x8*>(Ab + row * 64 + ps);
            }
            #pragma unroll
            for (int nf = 0; nf < 8; ++nf) {
                int nn = nf * 16 + li;
                int ps = ((kk * 4 + g) ^ (nn & 7)) * 8;
                bv[nf] = *reinterpret_cast<const bf16x8*>(Bsh + nn * 64 + ps);
            }
            #pragma unroll
            for (int mf = 0; mf < 3; ++mf)
                #pragma unroll
                for (int nf = 0; nf < 8; ++nf)
                    acc[mf][nf] = __builtin_amdgcn_mfma_f32_16x16x32_bf16(av[mf], bv[nf], acc[mf][nf], 0, 0, 0);
        }
    }
#undef PROJ_STAGE

    #pragma unroll
    for (int mf = 0; mf < 3; ++mf) {
        int m = w * 48 + mf * 16 + g * 4;
        #pragma unroll
        for (int nf = 0; nf < 8; ++nf) {
            int n = n0 + nf * 16 + li;
            f32x4 v = acc[mf][nf];
            #pragma unroll
            for (int r = 0; r < 4; ++r)
                out[((long)b * 384 + m + r) * 4096 + n] = v[r] + bp[m + r];
        }
    }
}

// ---------------- launch ----------------
extern "C" void kernel_launch(void* const* d_in, const int* in_sizes, int n_in,
                              void* d_out, int out_size, void* d_ws, size_t ws_size,
                              hipStream_t stream) {
    (void)in_sizes; (void)n_in; (void)out_size; (void)ws_size;
    const float* x  = (const float*)d_in[0];
    const float* Wq = (const float*)d_in[1];
    const float* sq = (const float*)d_in[2];
    const float* bq = (const float*)d_in[3];
    const float* Wk = (const float*)d_in[4];
    const float* sk = (const float*)d_in[5];
    const float* bk = (const float*)d_in[6];
    const float* Wv = (const float*)d_in[7];
    const float* sv = (const float*)d_in[8];
    const float* bv = (const float*)d_in[9];
    const float* Wp = (const float*)d_in[10];
    const float* sp = (const float*)d_in[11];
    const float* bp = (const float*)d_in[12];
    float* out = (float*)d_out;

    char* wsb = (char*)d_ws;
    unsigned short* Wqkv  = (unsigned short*)(wsb);              // 786432 B
    unsigned short* Wpf   = (unsigned short*)(wsb + 786432);     // 393216 B
    float*          bqkv  = (float*)(wsb + 1179648);             // 4096 B
    unsigned short* ctxT  = (unsigned short*)(wsb + 1183744);    // 262144 B
    float*          part  = (float*)(wsb + 1445888);             // 16777216 B
    float*          psums = (float*)(wsb + 18223104);            // 262144 B
    unsigned short* qT    = (unsigned short*)(wsb + 18485248);   // 16777216 B -> 35.3 MB total

    fold_weights_k<<<2308, 256, 0, stream>>>(Wq, sq, bq, Wk, sk, bk, Wv, sv, bv, Wp, sp,
                                             Wqkv, Wpf, bqkv);
    gemm_qkv_k<<<dim3(32, 8, 8), 256, 0, stream>>>(Wqkv, x, bqkv, qT, part, psums);
    ctx_reduce_k<<<512, 256, 0, stream>>>(part, psums, ctxT);
    proj_fused_k<<<dim3(32, 8), 512, 0, stream>>>(Wpf, qT, ctxT, bp, out);
}

// Round 17
// 88.071 us; speedup vs baseline: 1.7010x; 1.0134x over previous
//
#include <hip/hip_runtime.h>

typedef __attribute__((ext_vector_type(8))) short bf16x8;
typedef __attribute__((ext_vector_type(4))) float f32x4;
typedef __attribute__((ext_vector_type(4))) unsigned short us4;

__device__ __forceinline__ unsigned short f2bf(float f) {
    unsigned int u = __builtin_bit_cast(unsigned int, f);
    u = (u + 0x7FFFu + ((u >> 16) & 1u)) >> 16;
    return (unsigned short)u;
}
__device__ __forceinline__ float bf2f(unsigned short h) {
    return __builtin_bit_cast(float, (unsigned int)h << 16);
}

// ---------------- fold BN into weights, emit bf16; per-head packed row order ----------------
__global__ __launch_bounds__(256) void fold_weights_k(
    const float* __restrict__ Wq, const float* __restrict__ sq, const float* __restrict__ bq,
    const float* __restrict__ Wk, const float* __restrict__ sk, const float* __restrict__ bk,
    const float* __restrict__ Wv, const float* __restrict__ sv, const float* __restrict__ bv,
    const float* __restrict__ Wp, const float* __restrict__ sp,
    unsigned short* __restrict__ WqkvP, unsigned short* __restrict__ Wpf, float* __restrict__ bqkvP)
{
    int i = blockIdx.x * 256 + threadIdx.x;
    if (i < 393216) {                       // WqkvP [1024][384]
        int r = i / 384, c = i - r * 384;
        int head = r >> 7, t = r & 127;
        float w, s;
        if (t < 32)      { int ch = head * 32 + t;        w = Wq[ch * 384 + c]; s = sq[ch]; }
        else if (t < 64) { int ch = head * 32 + (t - 32); w = Wk[ch * 384 + c]; s = sk[ch]; }
        else             { int ch = head * 64 + (t - 64); w = Wv[ch * 384 + c]; s = sv[ch]; }
        WqkvP[i] = f2bf(w * s);
    } else if (i < 589824) {                // Wpf [384][512]
        int j = i - 393216;
        Wpf[j] = f2bf(Wp[j] * sp[j >> 9]);
    } else if (i < 590848) {
        int r = i - 589824;
        int head = r >> 7, t = r & 127;
        bqkvP[r] = (t < 32) ? bq[head * 32 + t]
                 : (t < 64) ? bk[head * 32 + (t - 32)]
                            : bv[head * 64 + (t - 64)];
    }
}

// ---------------- persistent-B fused QKV GEMM + context partials ----------------
// grid (32 chunks, 8 b) = 256 blocks (1/CU), 512 threads = 8 waves.
// Phase 1: x tile 128n x 384k loaded+packed ONCE -> Bp (96 KB, proven swizzle).
// Phase 2: 4 head-pairs x 12 K-tiles; waves 0-3 head a, 4-7 head b; A via 3x16KB
// gload_lds ring, depth-2, vmcnt(2), one barrier/tile. Epilogue per pair in A-buf region.
// LDS = 96 + 48 + 0.5 = 144.5 KB -> 1 block/CU.
__global__ __launch_bounds__(512, 2) void gemm_qkv_k(
    const unsigned short* __restrict__ A,     // WqkvP [1024][384] head-packed
    const float* __restrict__ x,              // [b][384][4096] f32
    const float* __restrict__ bias,           // bqkvP
    unsigned short* __restrict__ q_out,       // qT [b][4096][256]
    float* __restrict__ part,                 // [32][64][64 d][32 kd]
    float* __restrict__ psums)                // [32][64][32]
{
    __shared__ unsigned short Bp[12 * 4096];  // persistent B: 12 k-tiles x (64 lds-rows x 64)
    __shared__ unsigned short As[3 * 8192];   // A ring: 3 bufs x (2 heads x 4096); reused as Ksh/Vsh x2
    __shared__ float psl2[2][64];
    const int tid = threadIdx.x;
    const int lane = tid & 63;
    const int w = tid >> 6;                   // 0..7
    const int hw = w & 3, hg = w >> 2;        // wave-in-headgroup, head-in-pair
    const int wr = hw >> 1, wc = hw & 1;
    const int li = lane & 15, g = lane >> 4;
    const int b = blockIdx.y, chunk = blockIdx.x;
    const int n0 = chunk * 128;
    const float* xb = x + (long)b * 384 * 4096 + n0 + 2 * lane;

    // A granule map (per head-buf: 512 granules, tid 0..511 -> one granule per head)
    const int pA = tid >> 3, vA = (tid & 7) ^ (pA & 7);
    const long aoff = (long)(pA * 2 + (vA >> 2)) * 384 + (vA & 3) * 8;

#define ISSUE_A(hp, t) { const int _bf = (t) % 3; const long _k0 = (t) * 32; \
    const unsigned short* _a0 = A + (long)(2 * (hp)) * 128 * 384 + aoff + _k0; \
    __builtin_amdgcn_global_load_lds( \
        (const __attribute__((address_space(1))) void*)_a0, \
        (__attribute__((address_space(3))) void*)(As + _bf * 8192 + (size_t)tid * 8), 16, 0, 0); \
    __builtin_amdgcn_global_load_lds( \
        (const __attribute__((address_space(1))) void*)(_a0 + 128 * 384), \
        (__attribute__((address_space(3))) void*)(As + _bf * 8192 + 4096 + (size_t)tid * 8), 16, 0, 0); }

    // ---- phase 1: pack x once into Bp. Wave w handles k-slice ktb+(w>>2), channels (w&3)*8..+8
#define LOADX(ktb, breg) { const int _k0 = ((ktb) + hg) * 32 + hw * 8; \
    _Pragma("unroll") \
    for (int j = 0; j < 8; ++j) \
        breg[j] = *reinterpret_cast<const float2*>(xb + (long)(_k0 + j) * 4096); }
#define PACKX(ktb, breg) { \
    unsigned int pw0[4], pw1[4]; \
    _Pragma("unroll") \
    for (int j = 0; j < 4; ++j) { \
        asm("v_cvt_pk_bf16_f32 %0, %1, %2" : "=v"(pw0[j]) : "v"(breg[2*j].x), "v"(breg[2*j+1].x)); \
        asm("v_cvt_pk_bf16_f32 %0, %1, %2" : "=v"(pw1[j]) : "v"(breg[2*j].y), "v"(breg[2*j+1].y)); \
    } \
    uint4 q0 = {pw0[0], pw0[1], pw0[2], pw0[3]}; \
    uint4 q1 = {pw1[0], pw1[1], pw1[2], pw1[3]}; \
    int s0 = hw ^ (lane & 7), s1 = (4 + hw) ^ (lane & 7); \
    unsigned short* _bd = Bp + ((ktb) + hg) * 4096 + lane * 64; \
    *reinterpret_cast<uint4*>(_bd + s0 * 8) = q0; \
    *reinterpret_cast<uint4*>(_bd + s1 * 8) = q1; }

    {
        float2 ba[8], bb[8];
        LOADX(0, ba);
        #pragma unroll
        for (int ktb = 0; ktb < 12; ktb += 2) {
            if (ktb < 10) { if ((ktb >> 1) & 1) { LOADX(ktb + 2, ba) } else { LOADX(ktb + 2, bb) } }
            if ((ktb >> 1) & 1) { PACKX(ktb, bb) } else { PACKX(ktb, ba) }
        }
    }
#undef LOADX
#undef PACKX

    // prologue A for pair 0 (no barrier needed yet for gload_lds; ds_writes drained below)
    ISSUE_A(0, 0); ISSUE_A(0, 1);
    asm volatile("s_waitcnt lgkmcnt(0)\n\ts_barrier" ::: "memory");   // Bp visible to all waves
    __builtin_amdgcn_sched_barrier(0);

    for (int hp = 0; hp < 4; ++hp) {
        const int head = 2 * hp + hg;
        const int m0 = head * 128;

        f32x4 acc[4][4];
        #pragma unroll
        for (int i = 0; i < 4; ++i)
            #pragma unroll
            for (int j = 0; j < 4; ++j) acc[i][j] = (f32x4){0.f, 0.f, 0.f, 0.f};

        #pragma unroll
        for (int kt = 0; kt < 12; ++kt) {
            if (kt < 11) asm volatile("s_waitcnt vmcnt(2)\n\ts_barrier" ::: "memory");
            else         asm volatile("s_waitcnt vmcnt(0)\n\ts_barrier" ::: "memory");
            __builtin_amdgcn_sched_barrier(0);

            const unsigned short* Ab = As + (kt % 3) * 8192 + hg * 4096;
            const unsigned short* Bl = Bp + kt * 4096;

            bf16x8 av[4], bv[4];
            #pragma unroll
            for (int mf = 0; mf < 4; ++mf) {
                int r = wr * 64 + mf * 16 + li;
                int p = r >> 1;
                int slot = (((r & 1) * 4 + g) ^ (p & 7));
                av[mf] = *reinterpret_cast<const bf16x8*>(Ab + p * 64 + slot * 8);
            }
            #pragma unroll
            for (int nf = 0; nf < 4; ++nf) {
                int r = wc * 64 + nf * 16 + li;
                int p = r >> 1;
                int slot = (((r & 1) * 4 + g) ^ (p & 7));
                bv[nf] = *reinterpret_cast<const bf16x8*>(Bl + p * 64 + slot * 8);
            }
            if (kt < 10)      ISSUE_A(hp, kt + 2);
            __builtin_amdgcn_s_setprio(1);
            #pragma unroll
            for (int mf = 0; mf < 4; ++mf)
                #pragma unroll
                for (int nf = 0; nf < 4; ++nf)
                    acc[mf][nf] = __builtin_amdgcn_mfma_f32_16x16x32_bf16(av[mf], bv[nf], acc[mf][nf], 0, 0, 0);
            __builtin_amdgcn_s_setprio(0);
        }

        __syncthreads();   // all LDS reads done; A bufs reusable as Ksh/Vsh

        // LDS reuse per head: Ksh [32][128] + Vsh [64][128] (24 KB each head-group)
        unsigned short* Ksh = As + hg * 12288;
        unsigned short* Vsh = Ksh + 4096;
        float* psl = psl2[hg];

        if (wr == 0) {
            #pragma unroll
            for (int mf = 0; mf < 2; ++mf) {
                int ml = mf * 16 + g * 4;
                #pragma unroll
                for (int nf = 0; nf < 4; ++nf) {
                    int n = n0 + wc * 64 + nf * 16 + li;
                    f32x4 v = acc[mf][nf];
                    us4 o = { f2bf(v.x + bias[m0 + ml]),     f2bf(v.y + bias[m0 + ml + 1]),
                              f2bf(v.z + bias[m0 + ml + 2]), f2bf(v.w + bias[m0 + ml + 3]) };
                    *reinterpret_cast<us4*>(q_out + (((long)b * 4096 + n) << 8) + head * 32 + ml) = o;
                }
            }
            float rs[2][4] = {{0.f,0.f,0.f,0.f},{0.f,0.f,0.f,0.f}};
            #pragma unroll
            for (int mm = 0; mm < 2; ++mm) {
                #pragma unroll
                for (int nf = 0; nf < 4; ++nf) {
                    int nl = wc * 64 + nf * 16 + li;
                    f32x4 v = acc[mm + 2][nf];
                    #pragma unroll
                    for (int r = 0; r < 4; ++r) {
                        int kd = mm * 16 + g * 4 + r;
                        float e = __expf(v[r] + bias[m0 + 32 + kd]);
                        rs[mm][r] += e;
                        Ksh[kd * 128 + ((((nl >> 3) ^ (kd & 7)) << 3) | (nl & 7))] = f2bf(e);
                    }
                }
            }
            #pragma unroll
            for (int mm = 0; mm < 2; ++mm)
                #pragma unroll
                for (int r = 0; r < 4; ++r) {
                    float s = rs[mm][r];
                    s += __shfl_xor(s, 1); s += __shfl_xor(s, 2);
                    s += __shfl_xor(s, 4); s += __shfl_xor(s, 8);
                    if (li == 0) psl[wc * 32 + mm * 16 + g * 4 + r] = s;
                }
        } else {
            #pragma unroll
            for (int mf = 0; mf < 4; ++mf) {
                #pragma unroll
                for (int nf = 0; nf < 4; ++nf) {
                    int nl = wc * 64 + nf * 16 + li;
                    f32x4 v = acc[mf][nf];
                    #pragma unroll
                    for (int r = 0; r < 4; ++r) {
                        int d = mf * 16 + g * 4 + r;
                        Vsh[d * 128 + ((((nl >> 3) ^ (d & 7)) << 3) | (nl & 7))] =
                            f2bf(v[r] + bias[m0 + 64 + d]);
                    }
                }
            }
        }
        __syncthreads();

        // ---- mini-GEMM: ctx_part[d][kd] over n=128; wave hw owns d-cols hw*16..+16 of its head
        f32x4 c2[2] = {(f32x4){0.f,0.f,0.f,0.f}, (f32x4){0.f,0.f,0.f,0.f}};
        #pragma unroll
        for (int ks = 0; ks < 4; ++ks) {
            int rd = hw * 16 + li;
            bf16x8 a0 = *reinterpret_cast<const bf16x8*>(Ksh + li * 128        + ((((ks * 4 + g) ^ (li & 7)) << 3)));
            bf16x8 a1 = *reinterpret_cast<const bf16x8*>(Ksh + (16 + li) * 128 + ((((ks * 4 + g) ^ ((16 + li) & 7)) << 3)));
            bf16x8 bb = *reinterpret_cast<const bf16x8*>(Vsh + rd * 128        + ((((ks * 4 + g) ^ (rd & 7)) << 3)));
            c2[0] = __builtin_amdgcn_mfma_f32_16x16x32_bf16(a0, bb, c2[0], 0, 0, 0);
            c2[1] = __builtin_amdgcn_mfma_f32_16x16x32_bf16(a1, bb, c2[1], 0, 0, 0);
        }
        const int bh = b * 8 + head;
        const long pbase = ((long)chunk * 64 + bh) * 2048;
        #pragma unroll
        for (int mm = 0; mm < 2; ++mm)
            *reinterpret_cast<f32x4*>(&part[pbase + (long)(hw * 16 + li) * 32 + mm * 16 + g * 4]) = c2[mm];
        if (tid < 64)
            psums[((long)chunk * 64 + b * 8 + 2 * hp + (tid >> 5)) * 32 + (tid & 31)] =
                psl2[tid >> 5][tid & 31] + psl2[tid >> 5][32 + (tid & 31)];

        __syncthreads();   // epilogue LDS reads done; As reusable for next pair's A staging

        if (hp < 3) { ISSUE_A(hp + 1, 0); ISSUE_A(hp + 1, 1); }
    }
#undef ISSUE_A
}

// ---------------- reduce 32 chunks, normalize -> ctxT[bh][d][kd] bf16 (coalesced reads) ----------------
__global__ __launch_bounds__(256) void ctx_reduce_k(const float* __restrict__ part,
                                                    const float* __restrict__ psums,
                                                    unsigned short* __restrict__ ctxT)
{
    int t = blockIdx.x * 256 + threadIdx.x;   // < 131072
    int bh = t >> 11, i = t & 2047;           // i = d*32 + kd
    int kd = i & 31;
    float s = 0.f, den = 0.f;
    #pragma unroll
    for (int c = 0; c < 32; ++c) {
        s   += part[((long)c * 64 + bh) * 2048 + i];
        den += psums[((long)c * 64 + bh) * 32 + kd];
    }
    ctxT[t] = f2bf(s / den);
}

// ---------------- fused proj v3: tall-M block, softmax+attend once, GEMM ----------------
// grid (32 n-blocks, 8 b), 512 threads = 8 waves. LDS = 112 KB -> 1 block/CU.
__global__ __launch_bounds__(512, 2) void proj_fused_k(
    const unsigned short* __restrict__ Wpf,   // [384][512] bf16, k = h*64+d
    const unsigned short* __restrict__ qT,    // [b][4096][256] bf16 (raw q, pre-softmax)
    const unsigned short* __restrict__ ctxT,  // [b*8+h][64 d][32 kd] bf16
    const float* __restrict__ bp,
    float* __restrict__ out)                  // [b][384][4096] f32
{
    __shared__ unsigned short Bsh[128 * 64];
    __shared__ unsigned short As[2][384 * 64];
    const int tid = threadIdx.x, lane = tid & 63, w = tid >> 6;
    const int li = lane & 15, g = lane >> 4;
    const int b = blockIdx.y, n0 = blockIdx.x * 128;

#define PROJ_STAGE(buf, s) { \
    _Pragma("unroll") \
    for (int j = 0; j < 6; ++j) { \
        int idx = j * 512 + tid; \
        int r = idx >> 3; \
        int ls = ((idx & 7) ^ (r & 7)) * 8; \
        __builtin_amdgcn_global_load_lds( \
            (const __attribute__((address_space(1))) void*)(Wpf + (long)r * 512 + (s) * 64 + ls), \
            (__attribute__((address_space(3))) void*)(As[buf] + (size_t)idx * 8), 16, 0, 0); \
    } }

    PROJ_STAGE(0, 0);

    f32x4 acc[3][8];
    #pragma unroll
    for (int i = 0; i < 3; ++i)
        #pragma unroll
        for (int j = 0; j < 8; ++j) acc[i][j] = (f32x4){0.f, 0.f, 0.f, 0.f};

    for (int s = 0; s < 8; ++s) {
        const unsigned short* cb = ctxT + ((long)b * 8 + s) * 2048;
        bf16x8 ca[4], pb;
        #pragma unroll
        for (int df = 0; df < 4; ++df)
            ca[df] = *reinterpret_cast<const bf16x8*>(cb + (df * 16 + li) * 32 + g * 8);
        {
            int n = n0 + w * 16 + li;
            bf16x8 r = *reinterpret_cast<const bf16x8*>(
                qT + (((long)b * 4096 + n) << 8) + s * 32 + g * 8);
            float f[8];
            float mx = -1e30f;
            #pragma unroll
            for (int j = 0; j < 8; ++j) { f[j] = bf2f((unsigned short)r[j]); mx = fmaxf(mx, f[j]); }
            mx = fmaxf(mx, __shfl_xor(mx, 16));
            mx = fmaxf(mx, __shfl_xor(mx, 32));
            float sm = 0.f;
            #pragma unroll
            for (int j = 0; j < 8; ++j) { f[j] = __expf(f[j] - mx); sm += f[j]; }
            sm += __shfl_xor(sm, 16);
            sm += __shfl_xor(sm, 32);
            float inv = 1.f / sm;
            #pragma unroll
            for (int j = 0; j < 8; ++j) pb[j] = (short)f2bf(f[j] * inv);
        }
        us4 bw[4];
        #pragma unroll
        for (int df = 0; df < 4; ++df) {
            f32x4 d = (f32x4){0.f, 0.f, 0.f, 0.f};
            d = __builtin_amdgcn_mfma_f32_16x16x32_bf16(ca[df], pb, d, 0, 0, 0);
            bw[df] = (us4){ f2bf(fmaxf(d.x, 0.f)), f2bf(fmaxf(d.y, 0.f)),
                            f2bf(fmaxf(d.z, 0.f)), f2bf(fmaxf(d.w, 0.f)) };
        }

        __syncthreads();

        if (s < 7) PROJ_STAGE((s + 1) & 1, s + 1);

        #pragma unroll
        for (int df = 0; df < 4; ++df) {
            int n = w * 16 + li;
            int slot = (df * 2 + (g >> 1)) ^ (n & 7);
            *reinterpret_cast<us4*>(Bsh + n * 64 + slot * 8 + (g & 1) * 4) = bw[df];
        }

        asm volatile("s_waitcnt lgkmcnt(0)\n\ts_barrier" ::: "memory");
        __builtin_amdgcn_sched_barrier(0);

        const unsigned short* Ab = As[s & 1];
        #pragma unroll
        for (int kk = 0; kk < 2; ++kk) {
            bf16x8 av[3], bv[8];
            #pragma unroll
            for (int mf = 0; mf < 3; ++mf) {
                int row = w * 48 + mf * 16 + li;
                int ps = ((kk * 4 + g) ^ (row & 7)) * 8;
                av[mf] = *reinterpret_cast<const bf16x8*>(Ab + row * 64 + ps);
            }
            #pragma unroll
            for (int nf = 0; nf < 8; ++nf) {
                int nn = nf * 16 + li;
                int ps = ((kk * 4 + g) ^ (nn & 7)) * 8;
                bv[nf] = *reinterpret_cast<const bf16x8*>(Bsh + nn * 64 + ps);
            }
            #pragma unroll
            for (int mf = 0; mf < 3; ++mf)
                #pragma unroll
                for (int nf = 0; nf < 8; ++nf)
                    acc[mf][nf] = __builtin_amdgcn_mfma_f32_16x16x32_bf16(av[mf], bv[nf], acc[mf][nf], 0, 0, 0);
        }
    }
#undef PROJ_STAGE

    #pragma unroll
    for (int mf = 0; mf < 3; ++mf) {
        int m = w * 48 + mf * 16 + g * 4;
        #pragma unroll
        for (int nf = 0; nf < 8; ++nf) {
            int n = n0 + nf * 16 + li;
            f32x4 v = acc[mf][nf];
            #pragma unroll
            for (int r = 0; r < 4; ++r)
                out[((long)b * 384 + m + r) * 4096 + n] = v[r] + bp[m + r];
        }
    }
}

// ---------------- launch ----------------
extern "C" void kernel_launch(void* const* d_in, const int* in_sizes, int n_in,
                              void* d_out, int out_size, void* d_ws, size_t ws_size,
                              hipStream_t stream) {
    (void)in_sizes; (void)n_in; (void)out_size; (void)ws_size;
    const float* x  = (const float*)d_in[0];
    const float* Wq = (const float*)d_in[1];
    const float* sq = (const float*)d_in[2];
    const float* bq = (const float*)d_in[3];
    const float* Wk = (const float*)d_in[4];
    const float* sk = (const float*)d_in[5];
    const float* bk = (const float*)d_in[6];
    const float* Wv = (const float*)d_in[7];
    const float* sv = (const float*)d_in[8];
    const float* bv = (const float*)d_in[9];
    const float* Wp = (const float*)d_in[10];
    const float* sp = (const float*)d_in[11];
    const float* bp = (const float*)d_in[12];
    float* out = (float*)d_out;

    char* wsb = (char*)d_ws;
    unsigned short* Wqkv  = (unsigned short*)(wsb);              // 786432 B
    unsigned short* Wpf   = (unsigned short*)(wsb + 786432);     // 393216 B
    float*          bqkv  = (float*)(wsb + 1179648);             // 4096 B
    unsigned short* ctxT  = (unsigned short*)(wsb + 1183744);    // 262144 B
    float*          part  = (float*)(wsb + 1445888);             // 16777216 B
    float*          psums = (float*)(wsb + 18223104);            // 262144 B
    unsigned short* qT    = (unsigned short*)(wsb + 18485248);   // 16777216 B -> 35.3 MB total

    fold_weights_k<<<2308, 256, 0, stream>>>(Wq, sq, bq, Wk, sk, bk, Wv, sv, bv, Wp, sp,
                                             Wqkv, Wpf, bqkv);
    gemm_qkv_k<<<dim3(32, 8), 512, 0, stream>>>(Wqkv, x, bqkv, qT, part, psums);
    ctx_reduce_k<<<512, 256, 0, stream>>>(part, psums, ctxT);
    proj_fused_k<<<dim3(32, 8), 512, 0, stream>>>(Wpf, qT, ctxT, bp, out);
}